// Round 5
// baseline (256.138 us; speedup 1.0000x reference)
//
#include <hip/hip_runtime.h>

#define N_NODES 50000
#define N_EDGES 800000
#define IN_DIM 16
#define OUT_DIM 16
#define N_RELS 90
#define N_BASES 30

#define DOTS_BLOCKS 196   // 196*256 = 50176 >= 50000
#define LINK_BLOCKS 3125  // 3125*256 = 800000

__device__ __forceinline__ float4 shfl_xor4(float4 v, int m) {
    float4 r;
    r.x = __shfl_xor(v.x, m); r.y = __shfl_xor(v.y, m);
    r.z = __shfl_xor(v.z, m); r.w = __shfl_xor(v.w, m);
    return r;
}

// ---------------------------------------------------------------------------
// Prep: W_rel (basis recombination, reference reshape semantics) + folded
// attention vectors a1,a2,a3 (Ws^T @ Wa chunks).
// ---------------------------------------------------------------------------
__global__ __launch_bounds__(256) void prep_kernel(
    const float* __restrict__ Ws,      // [16,16]  (out,in)
    const float* __restrict__ Wa,      // [1,48]
    const float* __restrict__ weight,  // [30,16,16] flat
    const float* __restrict__ w_comp,  // [90,30]
    float* __restrict__ Wrel,          // [90*256]
    float* __restrict__ avec)          // [48]
{
    int f = blockIdx.x * blockDim.x + threadIdx.x;
    if (f < N_RELS * IN_DIM * OUT_DIM) {
        int a   = f / (N_RELS * OUT_DIM);
        int rem = f % (N_RELS * OUT_DIM);
        int r   = rem / OUT_DIM;
        int o   = rem % OUT_DIM;
        float acc = 0.f;
        #pragma unroll
        for (int b = 0; b < N_BASES; ++b)
            acc += w_comp[r * N_BASES + b] * weight[a * (N_BASES * OUT_DIM) + b * OUT_DIM + o];
        Wrel[f] = acc;
    } else if (f < N_RELS * IN_DIM * OUT_DIM + 48) {
        int g = f - N_RELS * IN_DIM * OUT_DIM;
        int k = g / IN_DIM;
        int i = g % IN_DIM;
        float acc = 0.f;
        #pragma unroll
        for (int o = 0; o < OUT_DIM; ++o)
            acc += Wa[k * OUT_DIM + o] * Ws[o * IN_DIM + i];
        avec[g] = acc;
    }
}

// ---------------------------------------------------------------------------
// Fused: per-node score dots (first DOTS_BLOCKS blocks) + linked-list build
// (remaining blocks): old = atomicExch(head[dst], e); next[e] = old.
// ---------------------------------------------------------------------------
__global__ __launch_bounds__(256) void dots_link_kernel(
    const float* __restrict__ h,
    const float* __restrict__ avec,
    float2* __restrict__ s13,
    const int* __restrict__ dst,
    int* __restrict__ head,
    int* __restrict__ next)
{
    int b = blockIdx.x;
    if (b < DOTS_BLOCKS) {
        int n = b * 256 + threadIdx.x;
        if (n >= N_NODES) return;
        const float4* p = (const float4*)(h + (size_t)n * IN_DIM);
        float d1 = 0.f, d3 = 0.f;
        #pragma unroll
        for (int i = 0; i < 4; ++i) {
            float4 v = p[i];
            d1 += v.x * avec[4*i+0] + v.y * avec[4*i+1] + v.z * avec[4*i+2] + v.w * avec[4*i+3];
            d3 += v.x * avec[32+4*i+0] + v.y * avec[32+4*i+1] + v.z * avec[32+4*i+2] + v.w * avec[32+4*i+3];
        }
        s13[n] = make_float2(d1, d3);
    } else {
        int e = (b - DOTS_BLOCKS) * 256 + threadIdx.x;
        if (e < N_EDGES) {
            int d = dst[e];
            int old = atomicExch(&head[d], e);
            next[e] = old;
        }
    }
}

// ---------------------------------------------------------------------------
// Fused compute+reduce: ONE WAVE PER NODE. The wave chases the node's chain
// 16 ids at a time (uniform broadcast loads), processes 16 edges in parallel
// with 4 lanes/edge (line-dense he/h/W reads), butterfly-reduces in-register,
// writes hout[n] once. No msg buffer, no output atomics.
// ---------------------------------------------------------------------------
__global__ __launch_bounds__(256) void node_kernel(
    const float* __restrict__ h,
    const float* __restrict__ he,
    const int* __restrict__ src,
    const int* __restrict__ rel,
    const float* __restrict__ Wrel,
    const float* __restrict__ avec,
    const float2* __restrict__ s13,
    const int* __restrict__ head,
    const int* __restrict__ next,
    float* __restrict__ hout)
{
    int wave = threadIdx.x >> 6;
    int lane = threadIdx.x & 63;
    int n = blockIdx.x * 4 + wave;
    if (n >= N_NODES) return;

    int q = lane & 3;       // output quarter within edge group
    int g = lane >> 2;      // edge slot within batch (0..15)
    float s3n = s13[n].y;
    float4 av2 = *(const float4*)(avec + 16 + 4 * q);

    float4 acc = {0.f, 0.f, 0.f, 0.f};

    int cur = head[n];
    while (cur >= 0) {
        // ---- collect up to 16 edge ids; whole wave chases together ----
        int myid = -1;
        int k = 0;
        while (cur >= 0 && k < 16) {
            if (g == k) myid = cur;
            cur = next[cur];   // same addr across wave -> 1 broadcast request
            ++k;
        }
        bool act = (myid >= 0);
        int e = act ? myid : 0;

        // ---- gathers: 64B per group (line-dense) ----
        int s = src[e];
        int r = rel[e];
        float4 heq = *(const float4*)(he + (size_t)e * IN_DIM + q * 4);
        float4 hq  = *(const float4*)(h  + (size_t)s * IN_DIM + q * 4);
        float s1 = s13[s].x;

        // ---- score ----
        float pd = heq.x * av2.x + heq.y * av2.y + heq.z * av2.z + heq.w * av2.w;
        pd += __shfl_xor(pd, 1);
        pd += __shfl_xor(pd, 2);
        float score = s1 + s3n + pd;

        // ---- allgather h[src] row across the 4 lanes of the group ----
        float4 o1 = shfl_xor4(hq, 1);
        float4 o2 = shfl_xor4(hq, 2);
        float4 o3 = shfl_xor4(o1, 2);
        bool q0 = (q == 0), q1 = (q == 1), q2 = (q == 2);
        float4 row0 = q0 ? hq : q1 ? o1 : q2 ? o2 : o3;
        float4 row1 = q0 ? o1 : q1 ? hq : q2 ? o3 : o2;
        float4 row2 = q0 ? o2 : q1 ? o3 : q2 ? hq : o1;
        float4 row3 = q0 ? o3 : q1 ? o2 : q2 ? o1 : hq;
        float hs[16] = {row0.x,row0.y,row0.z,row0.w, row1.x,row1.y,row1.z,row1.w,
                        row2.x,row2.y,row2.z,row2.w, row3.x,row3.y,row3.z,row3.w};

        // ---- matvec: lane's output quarter; W reads 64B/group from L2 ----
        const float4* W4 = (const float4*)(Wrel + (size_t)r * 256) + q;
        float4 m = {0.f, 0.f, 0.f, 0.f};
        #pragma unroll
        for (int i = 0; i < 16; ++i) {
            float4 w = W4[i * 4];
            float hv = hs[i];
            m.x += hv * w.x; m.y += hv * w.y; m.z += hv * w.z; m.w += hv * w.w;
        }
        if (act) {
            acc.x += m.x * score; acc.y += m.y * score;
            acc.z += m.z * score; acc.w += m.w * score;
        }
    }

    // ---- reduce the 16 edge slots: butterfly over group dimension ----
    #pragma unroll
    for (int msk = 4; msk <= 32; msk <<= 1) {
        acc.x += __shfl_xor(acc.x, msk);
        acc.y += __shfl_xor(acc.y, msk);
        acc.z += __shfl_xor(acc.z, msk);
        acc.w += __shfl_xor(acc.w, msk);
    }
    if (lane < 4)   // lane == quarter index
        *(float4*)(hout + (size_t)n * OUT_DIM + lane * 4) = acc;
}

// ---------------------------------------------------------------------------
// Fallback (ws too small): direct atomic scatter.
// ---------------------------------------------------------------------------
__global__ __launch_bounds__(256) void edge_atomic_kernel(
    const float* __restrict__ h,
    const float* __restrict__ he,
    const int* __restrict__ src,
    const int* __restrict__ dst,
    const int* __restrict__ rel,
    const float* __restrict__ Wrel,
    const float* __restrict__ avec,
    float* __restrict__ hout)
{
    int e = blockIdx.x * blockDim.x + threadIdx.x;
    if (e >= N_EDGES) return;
    int s = src[e], d = dst[e], r = rel[e];
    float hs[IN_DIM];
    const float4* p = (const float4*)(h + (size_t)s * IN_DIM);
    #pragma unroll
    for (int i = 0; i < 4; ++i) {
        float4 v = p[i];
        hs[4*i+0] = v.x; hs[4*i+1] = v.y; hs[4*i+2] = v.z; hs[4*i+3] = v.w;
    }
    float score = 0.f;
    #pragma unroll
    for (int i = 0; i < IN_DIM; ++i) score += hs[i] * avec[i];
    const float4* qe = (const float4*)(he + (size_t)e * IN_DIM);
    #pragma unroll
    for (int i = 0; i < 4; ++i) {
        float4 v = qe[i];
        score += v.x * avec[16+4*i] + v.y * avec[17+4*i] + v.z * avec[18+4*i] + v.w * avec[19+4*i];
    }
    const float4* pd = (const float4*)(h + (size_t)d * IN_DIM);
    #pragma unroll
    for (int i = 0; i < 4; ++i) {
        float4 v = pd[i];
        score += v.x * avec[32+4*i] + v.y * avec[33+4*i] + v.z * avec[34+4*i] + v.w * avec[35+4*i];
    }
    float acc[OUT_DIM];
    #pragma unroll
    for (int o = 0; o < OUT_DIM; ++o) acc[o] = 0.f;
    const float* W = Wrel + (size_t)r * 256;
    #pragma unroll
    for (int i = 0; i < IN_DIM; ++i) {
        float hv = hs[i];
        #pragma unroll
        for (int o = 0; o < OUT_DIM; ++o) acc[o] += hv * W[i * OUT_DIM + o];
    }
    float* outp = hout + (size_t)d * OUT_DIM;
    #pragma unroll
    for (int o = 0; o < OUT_DIM; ++o) atomicAdd(outp + o, acc[o] * score);
}

extern "C" void kernel_launch(void* const* d_in, const int* in_sizes, int n_in,
                              void* d_out, int out_size, void* d_ws, size_t ws_size,
                              hipStream_t stream) {
    const float* h      = (const float*)d_in[0];
    const float* he     = (const float*)d_in[1];
    const float* Ws     = (const float*)d_in[2];
    const float* Wa     = (const float*)d_in[3];
    const float* weight = (const float*)d_in[4];
    const float* w_comp = (const float*)d_in[5];
    const int*   src    = (const int*)d_in[6];
    const int*   dst    = (const int*)d_in[7];
    const int*   rel    = (const int*)d_in[8];
    float* hout = (float*)d_out;

    // ws layout (float offsets)
    const size_t OFF_WREL = 0;        // 23040 f
    const size_t OFF_AVEC = 23040;    // 48 f (+16 pad)
    const size_t OFF_S13  = 23104;    // 100000 f (float2[50000])
    const size_t OFF_HEAD = 123104;   // 50000 i
    const size_t OFF_NEXT = 173104;   // 800000 i
    const size_t NEED_BYTES = (OFF_NEXT + (size_t)N_EDGES) * 4;

    float* wsf  = (float*)d_ws;
    float* Wrel = wsf + OFF_WREL;
    float* avec = wsf + OFF_AVEC;

    {
        int total = N_RELS * IN_DIM * OUT_DIM + 48;
        prep_kernel<<<(total + 255) / 256, 256, 0, stream>>>(Ws, Wa, weight, w_comp, Wrel, avec);
    }

    if (ws_size >= NEED_BYTES) {
        float2* s13 = (float2*)(wsf + OFF_S13);
        int* headp  = (int*)(wsf + OFF_HEAD);
        int* nextp  = (int*)(wsf + OFF_NEXT);

        hipMemsetAsync(headp, 0xFF, N_NODES * sizeof(int), stream);  // head = -1
        dots_link_kernel<<<DOTS_BLOCKS + LINK_BLOCKS, 256, 0, stream>>>(
            h, avec, s13, dst, headp, nextp);
        node_kernel<<<(N_NODES + 3) / 4, 256, 0, stream>>>(
            h, he, src, rel, Wrel, avec, s13, headp, nextp, hout);
    } else {
        hipMemsetAsync(d_out, 0, (size_t)out_size * sizeof(float), stream);
        edge_atomic_kernel<<<(N_EDGES + 255) / 256, 256, 0, stream>>>(
            h, he, src, dst, rel, Wrel, avec, hout);
    }
}

// Round 6
// 212.229 us; speedup vs baseline: 1.2069x; 1.2069x over previous
//
#include <hip/hip_runtime.h>

#define N_NODES 50000
#define N_EDGES 800000
#define IN_DIM 16
#define OUT_DIM 16
#define N_RELS 90
#define N_BASES 30

#define CAP 24          // bucket rows per node (avg deg 16; P(deg>24) ~ 2%)
#define OCAP 65536      // overflow entries (expected ~3k; 20x margin)

#define PREP_BLOCKS 91  // 91*256 = 23296 >= 23088
#define DOTS_BLOCKS 196 // 196*256 = 50176 >= 50000
#define ZERO_BLOCKS 196

__device__ __forceinline__ float4 shfl_xor4(float4 v, int m) {
    float4 r;
    r.x = __shfl_xor(v.x, m); r.y = __shfl_xor(v.y, m);
    r.z = __shfl_xor(v.z, m); r.w = __shfl_xor(v.w, m);
    return r;
}

// ---------------------------------------------------------------------------
// Setup: blocks [0,91) prep Wrel+avec; [91,287) node dots (local avec in LDS);
// [287,483) zero cnt; block 483 zeroes ocount.
// ---------------------------------------------------------------------------
__global__ __launch_bounds__(256) void setup_kernel(
    const float* __restrict__ Ws,      // [16,16]  (out,in)
    const float* __restrict__ Wa,      // [1,48]
    const float* __restrict__ weight,  // [30,16,16] flat
    const float* __restrict__ w_comp,  // [90,30]
    const float* __restrict__ h,
    float* __restrict__ Wrel,          // [90*256]
    float* __restrict__ avec,          // [48]
    float2* __restrict__ s13,          // [N_NODES]
    int* __restrict__ cnt,             // [N_NODES]
    int* __restrict__ ocount)
{
    int b = blockIdx.x;
    if (b < PREP_BLOCKS) {
        int f = b * 256 + threadIdx.x;
        if (f < N_RELS * IN_DIM * OUT_DIM) {
            int a   = f / (N_RELS * OUT_DIM);
            int rem = f % (N_RELS * OUT_DIM);
            int r   = rem / OUT_DIM;
            int o   = rem % OUT_DIM;
            float acc = 0.f;
            #pragma unroll
            for (int bb = 0; bb < N_BASES; ++bb)
                acc += w_comp[r * N_BASES + bb] * weight[a * (N_BASES * OUT_DIM) + bb * OUT_DIM + o];
            Wrel[f] = acc;
        } else if (f < N_RELS * IN_DIM * OUT_DIM + 48) {
            int g = f - N_RELS * IN_DIM * OUT_DIM;
            int k = g / IN_DIM;
            int i = g % IN_DIM;
            float acc = 0.f;
            #pragma unroll
            for (int o = 0; o < OUT_DIM; ++o)
                acc += Wa[k * OUT_DIM + o] * Ws[o * IN_DIM + i];
            avec[g] = acc;
        }
    } else if (b < PREP_BLOCKS + DOTS_BLOCKS) {
        // compute a1 (avec[0:16]) and a3 (avec[32:48]) locally - no cross-block dep
        __shared__ float la[48];
        if (threadIdx.x < 48) {
            int k = threadIdx.x / IN_DIM;
            int i = threadIdx.x % IN_DIM;
            float acc = 0.f;
            #pragma unroll
            for (int o = 0; o < OUT_DIM; ++o)
                acc += Wa[k * OUT_DIM + o] * Ws[o * IN_DIM + i];
            la[threadIdx.x] = acc;
        }
        __syncthreads();
        int n = (b - PREP_BLOCKS) * 256 + threadIdx.x;
        if (n >= N_NODES) return;
        const float4* p = (const float4*)(h + (size_t)n * IN_DIM);
        float d1 = 0.f, d3 = 0.f;
        #pragma unroll
        for (int i = 0; i < 4; ++i) {
            float4 v = p[i];
            d1 += v.x * la[4*i+0] + v.y * la[4*i+1] + v.z * la[4*i+2] + v.w * la[4*i+3];
            d3 += v.x * la[32+4*i+0] + v.y * la[32+4*i+1] + v.z * la[32+4*i+2] + v.w * la[32+4*i+3];
        }
        s13[n] = make_float2(d1, d3);
    } else if (b < PREP_BLOCKS + DOTS_BLOCKS + ZERO_BLOCKS) {
        int n = (b - PREP_BLOCKS - DOTS_BLOCKS) * 256 + threadIdx.x;
        if (n < N_NODES) cnt[n] = 0;
    } else {
        if (threadIdx.x == 0) *ocount = 0;
    }
}

// ---------------------------------------------------------------------------
// Edge compute (bucket): 4 lanes/edge, edge-sequential (he streamed in order).
// slot = atomicAdd(cnt[d]); row -> bucket[d*CAP+slot] (scattered 64B write,
// L2-merged) or overflow side array.
// ---------------------------------------------------------------------------
__global__ __launch_bounds__(256) void compute_bucket_kernel(
    const float* __restrict__ h,
    const float* __restrict__ he,
    const int* __restrict__ src,
    const int* __restrict__ dst,
    const int* __restrict__ rel,
    const float* __restrict__ Wrel,
    const float* __restrict__ avec,
    const float2* __restrict__ s13,
    int* __restrict__ cnt,
    float* __restrict__ bucket,   // [N_NODES*CAP*16]
    int* __restrict__ ocount,
    int* __restrict__ od,         // [OCAP]
    float* __restrict__ orow)     // [OCAP*16]
{
    int tid = blockIdx.x * 256 + threadIdx.x;
    int g = tid >> 2;           // edge
    int q = threadIdx.x & 3;    // quarter
    if (g >= N_EDGES) return;

    int s = src[g], d = dst[g], r = rel[g];

    float4 heq = *(const float4*)(he + (size_t)g * IN_DIM + q * 4);
    float4 hq  = *(const float4*)(h  + (size_t)s * IN_DIM + q * 4);
    float2 svs = s13[s];
    float2 svd = s13[d];

    // claim bucket slot early (lane 0 of group), broadcast
    int slot = 0;
    if (q == 0) slot = atomicAdd(&cnt[d], 1);
    slot = __shfl(slot, (threadIdx.x & 63) & ~3);

    // he-dot
    float4 av = *(const float4*)(avec + 16 + 4 * q);
    float pd = heq.x * av.x + heq.y * av.y + heq.z * av.z + heq.w * av.w;
    pd += __shfl_xor(pd, 1);
    pd += __shfl_xor(pd, 2);
    float score = svs.x + svd.y + pd;

    // allgather h[src] row across the 4 lanes
    float4 o1 = shfl_xor4(hq, 1);
    float4 o2 = shfl_xor4(hq, 2);
    float4 o3 = shfl_xor4(o1, 2);
    bool q0 = (q == 0), q1 = (q == 1), q2 = (q == 2);
    float4 row0 = q0 ? hq : q1 ? o1 : q2 ? o2 : o3;
    float4 row1 = q0 ? o1 : q1 ? hq : q2 ? o3 : o2;
    float4 row2 = q0 ? o2 : q1 ? o3 : q2 ? hq : o1;
    float4 row3 = q0 ? o3 : q1 ? o2 : q2 ? o1 : hq;
    float hs[16] = {row0.x,row0.y,row0.z,row0.w, row1.x,row1.y,row1.z,row1.w,
                    row2.x,row2.y,row2.z,row2.w, row3.x,row3.y,row3.z,row3.w};

    const float4* W4 = (const float4*)(Wrel + (size_t)r * 256) + q;
    float4 acc = {0.f, 0.f, 0.f, 0.f};
    #pragma unroll
    for (int i = 0; i < 16; ++i) {
        float4 w = W4[i * 4];
        float hv = hs[i];
        acc.x += hv * w.x; acc.y += hv * w.y; acc.z += hv * w.z; acc.w += hv * w.w;
    }
    acc.x *= score; acc.y *= score; acc.z *= score; acc.w *= score;

    if (slot < CAP) {
        *(float4*)(bucket + ((size_t)d * CAP + slot) * OUT_DIM + q * 4) = acc;
    } else {
        int oi = 0;
        if (q == 0) {
            oi = atomicAdd(ocount, 1);
            if (oi < OCAP) od[oi] = d;
        }
        oi = __shfl(oi, (threadIdx.x & 63) & ~3);
        if (oi < OCAP)
            *(float4*)(orow + (size_t)oi * OUT_DIM + q * 4) = acc;
    }
}

// ---------------------------------------------------------------------------
// Reduce (bucket): 16 threads/node, contiguous 1KB-per-node reads, one write.
// ---------------------------------------------------------------------------
__global__ __launch_bounds__(256) void reduce_bucket_kernel(
    const float* __restrict__ bucket,
    const int* __restrict__ cnt,
    float* __restrict__ hout)
{
    int tid = blockIdx.x * 256 + threadIdx.x;
    int n = tid >> 4;
    int o = tid & 15;
    if (n >= N_NODES) return;

    int deg = cnt[n];
    if (deg > CAP) deg = CAP;
    const float* bp = bucket + (size_t)n * CAP * OUT_DIM + o;
    float acc = 0.f;
    for (int j = 0; j < deg; ++j)
        acc += bp[j * OUT_DIM];
    hout[(size_t)n * OUT_DIM + o] = acc;
}

// ---------------------------------------------------------------------------
// Overflow flush: runs after reduce; few hundred entries expected.
// ---------------------------------------------------------------------------
__global__ __launch_bounds__(256) void overflow_kernel(
    const int* __restrict__ ocount,
    const int* __restrict__ od,
    const float* __restrict__ orow,
    float* __restrict__ hout)
{
    int m = *ocount;
    if (m > OCAP) m = OCAP;
    int total = m * OUT_DIM;
    for (int idx = blockIdx.x * 256 + threadIdx.x; idx < total; idx += gridDim.x * 256) {
        int i = idx >> 4;
        int o = idx & 15;
        atomicAdd(&hout[(size_t)od[i] * OUT_DIM + o], orow[(size_t)i * OUT_DIM + o]);
    }
}

// ===========================================================================
// CSR fallback path (R4, known-good 238us) - used if ws can't hold buckets.
// ===========================================================================
#define SCAN_BLOCKS 196
#define COUNT_BLOCKS 3125

__global__ __launch_bounds__(256) void dots_count_kernel(
    const float* __restrict__ h, const float* __restrict__ avec,
    float2* __restrict__ s13, const int* __restrict__ dst, int* __restrict__ cnt)
{
    int b = blockIdx.x;
    if (b < DOTS_BLOCKS) {
        int n = b * 256 + threadIdx.x;
        if (n >= N_NODES) return;
        const float4* p = (const float4*)(h + (size_t)n * IN_DIM);
        float d1 = 0.f, d3 = 0.f;
        #pragma unroll
        for (int i = 0; i < 4; ++i) {
            float4 v = p[i];
            d1 += v.x * avec[4*i+0] + v.y * avec[4*i+1] + v.z * avec[4*i+2] + v.w * avec[4*i+3];
            d3 += v.x * avec[32+4*i+0] + v.y * avec[32+4*i+1] + v.z * avec[32+4*i+2] + v.w * avec[32+4*i+3];
        }
        s13[n] = make_float2(d1, d3);
    } else {
        int e = (b - DOTS_BLOCKS) * 256 + threadIdx.x;
        if (e < N_EDGES) atomicAdd(&cnt[dst[e]], 1);
    }
}

__global__ __launch_bounds__(256) void scanA_kernel(
    const int* __restrict__ cnt, int* __restrict__ partial)
{
    __shared__ int sm[256];
    int idx = blockIdx.x * 256 + threadIdx.x;
    sm[threadIdx.x] = (idx < N_NODES) ? cnt[idx] : 0;
    __syncthreads();
    #pragma unroll
    for (int st = 128; st > 0; st >>= 1) {
        if (threadIdx.x < st) sm[threadIdx.x] += sm[threadIdx.x + st];
        __syncthreads();
    }
    if (threadIdx.x == 0) partial[blockIdx.x] = sm[0];
}

__global__ __launch_bounds__(256) void scanB_kernel(
    const int* __restrict__ partial, int* __restrict__ pbase, int* __restrict__ base)
{
    __shared__ int sm[256];
    int t = threadIdx.x;
    int v = (t < SCAN_BLOCKS) ? partial[t] : 0;
    sm[t] = v;
    __syncthreads();
    #pragma unroll
    for (int d = 1; d < 256; d <<= 1) {
        int u = (t >= d) ? sm[t - d] : 0;
        __syncthreads();
        sm[t] += u;
        __syncthreads();
    }
    if (t < SCAN_BLOCKS) pbase[t] = sm[t] - v;
    if (t == 0) base[N_NODES] = N_EDGES;
}

__global__ __launch_bounds__(256) void scanC_kernel(
    const int* __restrict__ cnt, const int* __restrict__ pbase,
    int* __restrict__ base, int* __restrict__ cursor)
{
    __shared__ int sm[256];
    int t = threadIdx.x;
    int idx = blockIdx.x * 256 + t;
    int v = (idx < N_NODES) ? cnt[idx] : 0;
    sm[t] = v;
    __syncthreads();
    #pragma unroll
    for (int d = 1; d < 256; d <<= 1) {
        int u = (t >= d) ? sm[t - d] : 0;
        __syncthreads();
        sm[t] += u;
        __syncthreads();
    }
    if (idx < N_NODES) {
        int b = pbase[blockIdx.x] + sm[t] - v;
        base[idx] = b;
        cursor[idx] = b;
    }
}

__global__ __launch_bounds__(256) void compute_csr_kernel(
    const float* __restrict__ h, const float* __restrict__ he,
    const int* __restrict__ src, const int* __restrict__ dst,
    const int* __restrict__ rel, const float* __restrict__ Wrel,
    const float* __restrict__ avec, const float2* __restrict__ s13,
    int* __restrict__ cursor, float* __restrict__ msg)
{
    int tid = blockIdx.x * 256 + threadIdx.x;
    int g = tid >> 2;
    int q = threadIdx.x & 3;
    if (g >= N_EDGES) return;
    int s = src[g], d = dst[g], r = rel[g];
    float4 heq = *(const float4*)(he + (size_t)g * IN_DIM + q * 4);
    float4 hq  = *(const float4*)(h  + (size_t)s * IN_DIM + q * 4);
    float2 svs = s13[s];
    float2 svd = s13[d];
    int pos = 0;
    if (q == 0) pos = atomicAdd(&cursor[d], 1);
    pos = __shfl(pos, (threadIdx.x & 63) & ~3);
    float4 av = *(const float4*)(avec + 16 + 4 * q);
    float pd = heq.x * av.x + heq.y * av.y + heq.z * av.z + heq.w * av.w;
    pd += __shfl_xor(pd, 1);
    pd += __shfl_xor(pd, 2);
    float score = svs.x + svd.y + pd;
    float4 o1 = shfl_xor4(hq, 1);
    float4 o2 = shfl_xor4(hq, 2);
    float4 o3 = shfl_xor4(o1, 2);
    bool q0 = (q == 0), q1 = (q == 1), q2 = (q == 2);
    float4 row0 = q0 ? hq : q1 ? o1 : q2 ? o2 : o3;
    float4 row1 = q0 ? o1 : q1 ? hq : q2 ? o3 : o2;
    float4 row2 = q0 ? o2 : q1 ? o3 : q2 ? hq : o1;
    float4 row3 = q0 ? o3 : q1 ? o2 : q2 ? o1 : hq;
    float hs[16] = {row0.x,row0.y,row0.z,row0.w, row1.x,row1.y,row1.z,row1.w,
                    row2.x,row2.y,row2.z,row2.w, row3.x,row3.y,row3.z,row3.w};
    const float4* W4 = (const float4*)(Wrel + (size_t)r * 256) + q;
    float4 acc = {0.f, 0.f, 0.f, 0.f};
    #pragma unroll
    for (int i = 0; i < 16; ++i) {
        float4 w = W4[i * 4];
        float hv = hs[i];
        acc.x += hv * w.x; acc.y += hv * w.y; acc.z += hv * w.z; acc.w += hv * w.w;
    }
    acc.x *= score; acc.y *= score; acc.z *= score; acc.w *= score;
    *(float4*)(msg + (size_t)pos * OUT_DIM + q * 4) = acc;
}

__global__ __launch_bounds__(256) void reduce_csr_kernel(
    const float* __restrict__ msg, const int* __restrict__ base,
    float* __restrict__ hout)
{
    int tid = blockIdx.x * 256 + threadIdx.x;
    int n = tid >> 4;
    int o = tid & 15;
    if (n >= N_NODES) return;
    int beg = base[n];
    int end = base[n + 1];
    float acc = 0.f;
    for (int j = beg; j < end; ++j)
        acc += msg[(size_t)j * OUT_DIM + o];
    hout[(size_t)n * OUT_DIM + o] = acc;
}

__global__ __launch_bounds__(256) void prep_kernel(
    const float* __restrict__ Ws, const float* __restrict__ Wa,
    const float* __restrict__ weight, const float* __restrict__ w_comp,
    float* __restrict__ Wrel, float* __restrict__ avec)
{
    int f = blockIdx.x * blockDim.x + threadIdx.x;
    if (f < N_RELS * IN_DIM * OUT_DIM) {
        int a   = f / (N_RELS * OUT_DIM);
        int rem = f % (N_RELS * OUT_DIM);
        int r   = rem / OUT_DIM;
        int o   = rem % OUT_DIM;
        float acc = 0.f;
        #pragma unroll
        for (int b = 0; b < N_BASES; ++b)
            acc += w_comp[r * N_BASES + b] * weight[a * (N_BASES * OUT_DIM) + b * OUT_DIM + o];
        Wrel[f] = acc;
    } else if (f < N_RELS * IN_DIM * OUT_DIM + 48) {
        int g = f - N_RELS * IN_DIM * OUT_DIM;
        int k = g / IN_DIM;
        int i = g % IN_DIM;
        float acc = 0.f;
        #pragma unroll
        for (int o = 0; o < OUT_DIM; ++o)
            acc += Wa[k * OUT_DIM + o] * Ws[o * IN_DIM + i];
        avec[g] = acc;
    }
}

extern "C" void kernel_launch(void* const* d_in, const int* in_sizes, int n_in,
                              void* d_out, int out_size, void* d_ws, size_t ws_size,
                              hipStream_t stream) {
    const float* h      = (const float*)d_in[0];
    const float* he     = (const float*)d_in[1];
    const float* Ws     = (const float*)d_in[2];
    const float* Wa     = (const float*)d_in[3];
    const float* weight = (const float*)d_in[4];
    const float* w_comp = (const float*)d_in[5];
    const int*   src    = (const int*)d_in[6];
    const int*   dst    = (const int*)d_in[7];
    const int*   rel    = (const int*)d_in[8];
    float* hout = (float*)d_out;

    // common ws prefix (float offsets)
    const size_t OFF_WREL = 0;         // 23040 f
    const size_t OFF_AVEC = 23040;     // 48 f (+16 pad)
    const size_t OFF_S13  = 23104;     // 100000 f
    const size_t OFF_CNT  = 123104;    // 50000 i

    // bucket path
    const size_t OFF_OCNT   = 173104;  // 16 i
    const size_t OFF_OD     = 173120;  // OCAP i
    const size_t OFF_OROW   = OFF_OD + OCAP;            // OCAP*16 f
    const size_t OFF_BUCKET = OFF_OROW + (size_t)OCAP * 16;  // N*CAP*16 f
    const size_t NEED_BUCKET = (OFF_BUCKET + (size_t)N_NODES * CAP * OUT_DIM) * 4;

    // CSR path
    const size_t OFF_BASE   = 173104;  // 50001 i (+15 pad)
    const size_t OFF_CURSOR = 223120;  // 50000 i
    const size_t OFF_PART   = 273120;  // 256 i
    const size_t OFF_PBASE  = 273376;  // 256 i
    const size_t OFF_MSG    = 273632;  // 12.8M f
    const size_t NEED_CSR   = (OFF_MSG + (size_t)N_EDGES * OUT_DIM) * 4;

    float* wsf  = (float*)d_ws;
    float* Wrel = wsf + OFF_WREL;
    float* avec = wsf + OFF_AVEC;
    float2* s13 = (float2*)(wsf + OFF_S13);
    int* cnt    = (int*)(wsf + OFF_CNT);

    if (ws_size >= NEED_BUCKET) {
        int* ocount   = (int*)(wsf + OFF_OCNT);
        int* od       = (int*)(wsf + OFF_OD);
        float* orow   = wsf + OFF_OROW;
        float* bucket = wsf + OFF_BUCKET;

        setup_kernel<<<PREP_BLOCKS + DOTS_BLOCKS + ZERO_BLOCKS + 1, 256, 0, stream>>>(
            Ws, Wa, weight, w_comp, h, Wrel, avec, s13, cnt, ocount);
        compute_bucket_kernel<<<(N_EDGES * 4 + 255) / 256, 256, 0, stream>>>(
            h, he, src, dst, rel, Wrel, avec, s13, cnt, bucket, ocount, od, orow);
        reduce_bucket_kernel<<<(N_NODES * OUT_DIM + 255) / 256, 256, 0, stream>>>(
            bucket, cnt, hout);
        overflow_kernel<<<32, 256, 0, stream>>>(ocount, od, orow, hout);
    } else if (ws_size >= NEED_CSR) {
        int* csbase = (int*)(wsf + OFF_BASE);
        int* cursor = (int*)(wsf + OFF_CURSOR);
        int* part   = (int*)(wsf + OFF_PART);
        int* pbase  = (int*)(wsf + OFF_PBASE);
        float* msg  = wsf + OFF_MSG;

        {
            int total = N_RELS * IN_DIM * OUT_DIM + 48;
            prep_kernel<<<(total + 255) / 256, 256, 0, stream>>>(Ws, Wa, weight, w_comp, Wrel, avec);
        }
        hipMemsetAsync(cnt, 0, N_NODES * sizeof(int), stream);
        dots_count_kernel<<<DOTS_BLOCKS + COUNT_BLOCKS, 256, 0, stream>>>(h, avec, s13, dst, cnt);
        scanA_kernel<<<SCAN_BLOCKS, 256, 0, stream>>>(cnt, part);
        scanB_kernel<<<1, 256, 0, stream>>>(part, pbase, csbase);
        scanC_kernel<<<SCAN_BLOCKS, 256, 0, stream>>>(cnt, pbase, csbase, cursor);
        compute_csr_kernel<<<(N_EDGES * 4 + 255) / 256, 256, 0, stream>>>(
            h, he, src, dst, rel, Wrel, avec, s13, cursor, msg);
        reduce_csr_kernel<<<(N_NODES * OUT_DIM + 255) / 256, 256, 0, stream>>>(msg, csbase, hout);
    }
}

// Round 7
// 202.215 us; speedup vs baseline: 1.2667x; 1.0495x over previous
//
#include <hip/hip_runtime.h>

#define N_NODES 50000
#define N_EDGES 800000
#define IN_DIM 16
#define OUT_DIM 16
#define N_RELS 90
#define N_BASES 30

#define CAP 24          // bucket rows per node (avg deg 16; P(deg>24) ~ 2%)
#define OCAP 65536      // overflow entries (expected ~3k; 20x margin)

#define PREP_BLOCKS 91  // 91*256 = 23296 >= 23088
#define DOTS_BLOCKS 196 // 196*256 = 50176 >= 50000
#define ZERO_BLOCKS 196

__device__ __forceinline__ float4 shfl_xor4(float4 v, int m) {
    float4 r;
    r.x = __shfl_xor(v.x, m); r.y = __shfl_xor(v.y, m);
    r.z = __shfl_xor(v.z, m); r.w = __shfl_xor(v.w, m);
    return r;
}

// ---------------------------------------------------------------------------
// Setup: blocks [0,91) prep Wrel+avec; [91,287) node dots (local avec in LDS);
// [287,483) zero cnt; block 483 zeroes ocount.
// ---------------------------------------------------------------------------
__global__ __launch_bounds__(256) void setup_kernel(
    const float* __restrict__ Ws,      // [16,16]  (out,in)
    const float* __restrict__ Wa,      // [1,48]
    const float* __restrict__ weight,  // [30,16,16] flat
    const float* __restrict__ w_comp,  // [90,30]
    const float* __restrict__ h,
    float* __restrict__ Wrel,          // [90*256]
    float* __restrict__ avec,          // [48]
    float2* __restrict__ s13,          // [N_NODES]
    int* __restrict__ cnt,             // [N_NODES]
    int* __restrict__ ocount)
{
    int b = blockIdx.x;
    if (b < PREP_BLOCKS) {
        int f = b * 256 + threadIdx.x;
        if (f < N_RELS * IN_DIM * OUT_DIM) {
            int a   = f / (N_RELS * OUT_DIM);
            int rem = f % (N_RELS * OUT_DIM);
            int r   = rem / OUT_DIM;
            int o   = rem % OUT_DIM;
            float acc = 0.f;
            #pragma unroll
            for (int bb = 0; bb < N_BASES; ++bb)
                acc += w_comp[r * N_BASES + bb] * weight[a * (N_BASES * OUT_DIM) + bb * OUT_DIM + o];
            Wrel[f] = acc;
        } else if (f < N_RELS * IN_DIM * OUT_DIM + 48) {
            int g = f - N_RELS * IN_DIM * OUT_DIM;
            int k = g / IN_DIM;
            int i = g % IN_DIM;
            float acc = 0.f;
            #pragma unroll
            for (int o = 0; o < OUT_DIM; ++o)
                acc += Wa[k * OUT_DIM + o] * Ws[o * IN_DIM + i];
            avec[g] = acc;
        }
    } else if (b < PREP_BLOCKS + DOTS_BLOCKS) {
        // compute a1 (avec[0:16]) and a3 (avec[32:48]) locally - no cross-block dep
        __shared__ float la[48];
        if (threadIdx.x < 48) {
            int k = threadIdx.x / IN_DIM;
            int i = threadIdx.x % IN_DIM;
            float acc = 0.f;
            #pragma unroll
            for (int o = 0; o < OUT_DIM; ++o)
                acc += Wa[k * OUT_DIM + o] * Ws[o * IN_DIM + i];
            la[threadIdx.x] = acc;
        }
        __syncthreads();
        int n = (b - PREP_BLOCKS) * 256 + threadIdx.x;
        if (n >= N_NODES) return;
        const float4* p = (const float4*)(h + (size_t)n * IN_DIM);
        float d1 = 0.f, d3 = 0.f;
        #pragma unroll
        for (int i = 0; i < 4; ++i) {
            float4 v = p[i];
            d1 += v.x * la[4*i+0] + v.y * la[4*i+1] + v.z * la[4*i+2] + v.w * la[4*i+3];
            d3 += v.x * la[32+4*i+0] + v.y * la[32+4*i+1] + v.z * la[32+4*i+2] + v.w * la[32+4*i+3];
        }
        s13[n] = make_float2(d1, d3);
    } else if (b < PREP_BLOCKS + DOTS_BLOCKS + ZERO_BLOCKS) {
        int n = (b - PREP_BLOCKS - DOTS_BLOCKS) * 256 + threadIdx.x;
        if (n < N_NODES) cnt[n] = 0;
    } else {
        if (threadIdx.x == 0) *ocount = 0;
    }
}

// ---------------------------------------------------------------------------
// Edge compute (bucket, 2 edges per 4-lane group): all loads for both edges
// issued up front (2x MLP); interleaved W/FMA loop; scattered 64B bucket
// writes (L2-merged) or overflow side array.
// Block covers 128 edges: e0 = blk*128 + grp, e1 = e0 + 64.
// ---------------------------------------------------------------------------
__global__ __launch_bounds__(256) void compute_bucket_kernel(
    const float* __restrict__ h,
    const float* __restrict__ he,
    const int* __restrict__ src,
    const int* __restrict__ dst,
    const int* __restrict__ rel,
    const float* __restrict__ Wrel,
    const float* __restrict__ avec,
    const float2* __restrict__ s13,
    int* __restrict__ cnt,
    float* __restrict__ bucket,   // [N_NODES*CAP*16]
    int* __restrict__ ocount,
    int* __restrict__ od,         // [OCAP]
    float* __restrict__ orow)     // [OCAP*16]
{
    const int t = threadIdx.x;
    const int q = t & 3;          // quarter
    const int grp = t >> 2;       // 0..63
    const int e0 = blockIdx.x * 128 + grp;   // N_EDGES % 128 == 0: always valid
    const int e1 = e0 + 64;

    // ---- indices (both edges) ----
    int s0 = src[e0], d0 = dst[e0], r0 = rel[e0];
    int s1 = src[e1], d1 = dst[e1], r1 = rel[e1];

    // ---- independent gathers, all in flight ----
    float4 heq0 = *(const float4*)(he + (size_t)e0 * IN_DIM + q * 4);
    float4 heq1 = *(const float4*)(he + (size_t)e1 * IN_DIM + q * 4);
    float4 hq0  = *(const float4*)(h  + (size_t)s0 * IN_DIM + q * 4);
    float4 hq1  = *(const float4*)(h  + (size_t)s1 * IN_DIM + q * 4);
    float2 svs0 = s13[s0], svd0 = s13[d0];
    float2 svs1 = s13[s1], svd1 = s13[d1];

    // ---- claim bucket slots early (lane 0 of group), broadcast ----
    int slot0 = 0, slot1 = 0;
    if (q == 0) {
        slot0 = atomicAdd(&cnt[d0], 1);
        slot1 = atomicAdd(&cnt[d1], 1);
    }
    int lbase = (t & 63) & ~3;
    slot0 = __shfl(slot0, lbase);
    slot1 = __shfl(slot1, lbase);

    // ---- scores ----
    float4 av = *(const float4*)(avec + 16 + 4 * q);
    float pd0 = heq0.x * av.x + heq0.y * av.y + heq0.z * av.z + heq0.w * av.w;
    float pd1 = heq1.x * av.x + heq1.y * av.y + heq1.z * av.z + heq1.w * av.w;
    pd0 += __shfl_xor(pd0, 1); pd0 += __shfl_xor(pd0, 2);
    pd1 += __shfl_xor(pd1, 1); pd1 += __shfl_xor(pd1, 2);
    float sc0 = svs0.x + svd0.y + pd0;
    float sc1 = svs1.x + svd1.y + pd1;

    // ---- allgather h[src] rows across the 4 lanes of the group ----
    bool q0 = (q == 0), q1 = (q == 1), q2 = (q == 2);
    float hs0[16], hs1[16];
    {
        float4 o1 = shfl_xor4(hq0, 1);
        float4 o2 = shfl_xor4(hq0, 2);
        float4 o3 = shfl_xor4(o1, 2);
        float4 row0 = q0 ? hq0 : q1 ? o1 : q2 ? o2 : o3;
        float4 row1 = q0 ? o1 : q1 ? hq0 : q2 ? o3 : o2;
        float4 row2 = q0 ? o2 : q1 ? o3 : q2 ? hq0 : o1;
        float4 row3 = q0 ? o3 : q1 ? o2 : q2 ? o1 : hq0;
        hs0[0]=row0.x; hs0[1]=row0.y; hs0[2]=row0.z; hs0[3]=row0.w;
        hs0[4]=row1.x; hs0[5]=row1.y; hs0[6]=row1.z; hs0[7]=row1.w;
        hs0[8]=row2.x; hs0[9]=row2.y; hs0[10]=row2.z; hs0[11]=row2.w;
        hs0[12]=row3.x; hs0[13]=row3.y; hs0[14]=row3.z; hs0[15]=row3.w;
    }
    {
        float4 o1 = shfl_xor4(hq1, 1);
        float4 o2 = shfl_xor4(hq1, 2);
        float4 o3 = shfl_xor4(o1, 2);
        float4 row0 = q0 ? hq1 : q1 ? o1 : q2 ? o2 : o3;
        float4 row1 = q0 ? o1 : q1 ? hq1 : q2 ? o3 : o2;
        float4 row2 = q0 ? o2 : q1 ? o3 : q2 ? hq1 : o1;
        float4 row3 = q0 ? o3 : q1 ? o2 : q2 ? o1 : hq1;
        hs1[0]=row0.x; hs1[1]=row0.y; hs1[2]=row0.z; hs1[3]=row0.w;
        hs1[4]=row1.x; hs1[5]=row1.y; hs1[6]=row1.z; hs1[7]=row1.w;
        hs1[8]=row2.x; hs1[9]=row2.y; hs1[10]=row2.z; hs1[11]=row2.w;
        hs1[12]=row3.x; hs1[13]=row3.y; hs1[14]=row3.z; hs1[15]=row3.w;
    }

    // ---- two interleaved matvecs (independent W streams) ----
    const float4* W0 = (const float4*)(Wrel + (size_t)r0 * 256) + q;
    const float4* W1 = (const float4*)(Wrel + (size_t)r1 * 256) + q;
    float4 a0 = {0.f,0.f,0.f,0.f}, a1 = {0.f,0.f,0.f,0.f};
    #pragma unroll
    for (int i = 0; i < 16; ++i) {
        float4 w0 = W0[i * 4];
        float4 w1 = W1[i * 4];
        float u = hs0[i], v = hs1[i];
        a0.x += u * w0.x; a0.y += u * w0.y; a0.z += u * w0.z; a0.w += u * w0.w;
        a1.x += v * w1.x; a1.y += v * w1.y; a1.z += v * w1.z; a1.w += v * w1.w;
    }
    a0.x *= sc0; a0.y *= sc0; a0.z *= sc0; a0.w *= sc0;
    a1.x *= sc1; a1.y *= sc1; a1.z *= sc1; a1.w *= sc1;

    // ---- stores ----
    if (slot0 < CAP) {
        *(float4*)(bucket + ((size_t)d0 * CAP + slot0) * OUT_DIM + q * 4) = a0;
    } else {
        int oi = 0;
        if (q == 0) { oi = atomicAdd(ocount, 1); if (oi < OCAP) od[oi] = d0; }
        oi = __shfl(oi, lbase);
        if (oi < OCAP) *(float4*)(orow + (size_t)oi * OUT_DIM + q * 4) = a0;
    }
    if (slot1 < CAP) {
        *(float4*)(bucket + ((size_t)d1 * CAP + slot1) * OUT_DIM + q * 4) = a1;
    } else {
        int oi = 0;
        if (q == 0) { oi = atomicAdd(ocount, 1); if (oi < OCAP) od[oi] = d1; }
        oi = __shfl(oi, lbase);
        if (oi < OCAP) *(float4*)(orow + (size_t)oi * OUT_DIM + q * 4) = a1;
    }
}

// ---------------------------------------------------------------------------
// Reduce (bucket): 4 lanes/node, float4 reads (deg independent loads), one
// float4 write per lane.
// ---------------------------------------------------------------------------
__global__ __launch_bounds__(256) void reduce_bucket_kernel(
    const float* __restrict__ bucket,
    const int* __restrict__ cnt,
    float* __restrict__ hout)
{
    int tid = blockIdx.x * 256 + threadIdx.x;
    int n = tid >> 2;
    int q = tid & 3;
    if (n >= N_NODES) return;

    int deg = cnt[n];
    if (deg > CAP) deg = CAP;
    const float4* bp = (const float4*)(bucket + (size_t)n * CAP * OUT_DIM) + q;
    float4 acc = {0.f, 0.f, 0.f, 0.f};
    for (int j = 0; j < deg; ++j) {
        float4 v = bp[j * 4];
        acc.x += v.x; acc.y += v.y; acc.z += v.z; acc.w += v.w;
    }
    *(float4*)(hout + (size_t)n * OUT_DIM + q * 4) = acc;
}

// ---------------------------------------------------------------------------
// Overflow flush: runs after reduce; few hundred entries expected.
// ---------------------------------------------------------------------------
__global__ __launch_bounds__(256) void overflow_kernel(
    const int* __restrict__ ocount,
    const int* __restrict__ od,
    const float* __restrict__ orow,
    float* __restrict__ hout)
{
    int m = *ocount;
    if (m > OCAP) m = OCAP;
    int total = m * OUT_DIM;
    for (int idx = blockIdx.x * 256 + threadIdx.x; idx < total; idx += gridDim.x * 256) {
        int i = idx >> 4;
        int o = idx & 15;
        atomicAdd(&hout[(size_t)od[i] * OUT_DIM + o], orow[(size_t)i * OUT_DIM + o]);
    }
}

// ===========================================================================
// CSR fallback path (R4, known-good) - used if ws can't hold buckets.
// ===========================================================================
#define SCAN_BLOCKS 196
#define COUNT_BLOCKS 3125

__global__ __launch_bounds__(256) void dots_count_kernel(
    const float* __restrict__ h, const float* __restrict__ avec,
    float2* __restrict__ s13, const int* __restrict__ dst, int* __restrict__ cnt)
{
    int b = blockIdx.x;
    if (b < DOTS_BLOCKS) {
        int n = b * 256 + threadIdx.x;
        if (n >= N_NODES) return;
        const float4* p = (const float4*)(h + (size_t)n * IN_DIM);
        float d1 = 0.f, d3 = 0.f;
        #pragma unroll
        for (int i = 0; i < 4; ++i) {
            float4 v = p[i];
            d1 += v.x * avec[4*i+0] + v.y * avec[4*i+1] + v.z * avec[4*i+2] + v.w * avec[4*i+3];
            d3 += v.x * avec[32+4*i+0] + v.y * avec[32+4*i+1] + v.z * avec[32+4*i+2] + v.w * avec[32+4*i+3];
        }
        s13[n] = make_float2(d1, d3);
    } else {
        int e = (b - DOTS_BLOCKS) * 256 + threadIdx.x;
        if (e < N_EDGES) atomicAdd(&cnt[dst[e]], 1);
    }
}

__global__ __launch_bounds__(256) void scanA_kernel(
    const int* __restrict__ cnt, int* __restrict__ partial)
{
    __shared__ int sm[256];
    int idx = blockIdx.x * 256 + threadIdx.x;
    sm[threadIdx.x] = (idx < N_NODES) ? cnt[idx] : 0;
    __syncthreads();
    #pragma unroll
    for (int st = 128; st > 0; st >>= 1) {
        if (threadIdx.x < st) sm[threadIdx.x] += sm[threadIdx.x + st];
        __syncthreads();
    }
    if (threadIdx.x == 0) partial[blockIdx.x] = sm[0];
}

__global__ __launch_bounds__(256) void scanB_kernel(
    const int* __restrict__ partial, int* __restrict__ pbase, int* __restrict__ base)
{
    __shared__ int sm[256];
    int t = threadIdx.x;
    int v = (t < SCAN_BLOCKS) ? partial[t] : 0;
    sm[t] = v;
    __syncthreads();
    #pragma unroll
    for (int d = 1; d < 256; d <<= 1) {
        int u = (t >= d) ? sm[t - d] : 0;
        __syncthreads();
        sm[t] += u;
        __syncthreads();
    }
    if (t < SCAN_BLOCKS) pbase[t] = sm[t] - v;
    if (t == 0) base[N_NODES] = N_EDGES;
}

__global__ __launch_bounds__(256) void scanC_kernel(
    const int* __restrict__ cnt, const int* __restrict__ pbase,
    int* __restrict__ base, int* __restrict__ cursor)
{
    __shared__ int sm[256];
    int t = threadIdx.x;
    int idx = blockIdx.x * 256 + t;
    int v = (idx < N_NODES) ? cnt[idx] : 0;
    sm[t] = v;
    __syncthreads();
    #pragma unroll
    for (int d = 1; d < 256; d <<= 1) {
        int u = (t >= d) ? sm[t - d] : 0;
        __syncthreads();
        sm[t] += u;
        __syncthreads();
    }
    if (idx < N_NODES) {
        int b = pbase[blockIdx.x] + sm[t] - v;
        base[idx] = b;
        cursor[idx] = b;
    }
}

__global__ __launch_bounds__(256) void compute_csr_kernel(
    const float* __restrict__ h, const float* __restrict__ he,
    const int* __restrict__ src, const int* __restrict__ dst,
    const int* __restrict__ rel, const float* __restrict__ Wrel,
    const float* __restrict__ avec, const float2* __restrict__ s13,
    int* __restrict__ cursor, float* __restrict__ msg)
{
    int tid = blockIdx.x * 256 + threadIdx.x;
    int g = tid >> 2;
    int q = threadIdx.x & 3;
    if (g >= N_EDGES) return;
    int s = src[g], d = dst[g], r = rel[g];
    float4 heq = *(const float4*)(he + (size_t)g * IN_DIM + q * 4);
    float4 hq  = *(const float4*)(h  + (size_t)s * IN_DIM + q * 4);
    float2 svs = s13[s];
    float2 svd = s13[d];
    int pos = 0;
    if (q == 0) pos = atomicAdd(&cursor[d], 1);
    pos = __shfl(pos, (threadIdx.x & 63) & ~3);
    float4 av = *(const float4*)(avec + 16 + 4 * q);
    float pd = heq.x * av.x + heq.y * av.y + heq.z * av.z + heq.w * av.w;
    pd += __shfl_xor(pd, 1);
    pd += __shfl_xor(pd, 2);
    float score = svs.x + svd.y + pd;
    float4 o1 = shfl_xor4(hq, 1);
    float4 o2 = shfl_xor4(hq, 2);
    float4 o3 = shfl_xor4(o1, 2);
    bool q0 = (q == 0), q1 = (q == 1), q2 = (q == 2);
    float4 row0 = q0 ? hq : q1 ? o1 : q2 ? o2 : o3;
    float4 row1 = q0 ? o1 : q1 ? hq : q2 ? o3 : o2;
    float4 row2 = q0 ? o2 : q1 ? o3 : q2 ? hq : o1;
    float4 row3 = q0 ? o3 : q1 ? o2 : q2 ? o1 : hq;
    float hs[16] = {row0.x,row0.y,row0.z,row0.w, row1.x,row1.y,row1.z,row1.w,
                    row2.x,row2.y,row2.z,row2.w, row3.x,row3.y,row3.z,row3.w};
    const float4* W4 = (const float4*)(Wrel + (size_t)r * 256) + q;
    float4 acc = {0.f, 0.f, 0.f, 0.f};
    #pragma unroll
    for (int i = 0; i < 16; ++i) {
        float4 w = W4[i * 4];
        float hv = hs[i];
        acc.x += hv * w.x; acc.y += hv * w.y; acc.z += hv * w.z; acc.w += hv * w.w;
    }
    acc.x *= score; acc.y *= score; acc.z *= score; acc.w *= score;
    *(float4*)(msg + (size_t)pos * OUT_DIM + q * 4) = acc;
}

__global__ __launch_bounds__(256) void reduce_csr_kernel(
    const float* __restrict__ msg, const int* __restrict__ base,
    float* __restrict__ hout)
{
    int tid = blockIdx.x * 256 + threadIdx.x;
    int n = tid >> 4;
    int o = tid & 15;
    if (n >= N_NODES) return;
    int beg = base[n];
    int end = base[n + 1];
    float acc = 0.f;
    for (int j = beg; j < end; ++j)
        acc += msg[(size_t)j * OUT_DIM + o];
    hout[(size_t)n * OUT_DIM + o] = acc;
}

__global__ __launch_bounds__(256) void prep_kernel(
    const float* __restrict__ Ws, const float* __restrict__ Wa,
    const float* __restrict__ weight, const float* __restrict__ w_comp,
    float* __restrict__ Wrel, float* __restrict__ avec)
{
    int f = blockIdx.x * blockDim.x + threadIdx.x;
    if (f < N_RELS * IN_DIM * OUT_DIM) {
        int a   = f / (N_RELS * OUT_DIM);
        int rem = f % (N_RELS * OUT_DIM);
        int r   = rem / OUT_DIM;
        int o   = rem % OUT_DIM;
        float acc = 0.f;
        #pragma unroll
        for (int b = 0; b < N_BASES; ++b)
            acc += w_comp[r * N_BASES + b] * weight[a * (N_BASES * OUT_DIM) + b * OUT_DIM + o];
        Wrel[f] = acc;
    } else if (f < N_RELS * IN_DIM * OUT_DIM + 48) {
        int g = f - N_RELS * IN_DIM * OUT_DIM;
        int k = g / IN_DIM;
        int i = g % IN_DIM;
        float acc = 0.f;
        #pragma unroll
        for (int o = 0; o < OUT_DIM; ++o)
            acc += Wa[k * OUT_DIM + o] * Ws[o * IN_DIM + i];
        avec[g] = acc;
    }
}

extern "C" void kernel_launch(void* const* d_in, const int* in_sizes, int n_in,
                              void* d_out, int out_size, void* d_ws, size_t ws_size,
                              hipStream_t stream) {
    const float* h      = (const float*)d_in[0];
    const float* he     = (const float*)d_in[1];
    const float* Ws     = (const float*)d_in[2];
    const float* Wa     = (const float*)d_in[3];
    const float* weight = (const float*)d_in[4];
    const float* w_comp = (const float*)d_in[5];
    const int*   src    = (const int*)d_in[6];
    const int*   dst    = (const int*)d_in[7];
    const int*   rel    = (const int*)d_in[8];
    float* hout = (float*)d_out;

    // common ws prefix (float offsets)
    const size_t OFF_WREL = 0;         // 23040 f
    const size_t OFF_AVEC = 23040;     // 48 f (+16 pad)
    const size_t OFF_S13  = 23104;     // 100000 f
    const size_t OFF_CNT  = 123104;    // 50000 i

    // bucket path
    const size_t OFF_OCNT   = 173104;  // 16 i
    const size_t OFF_OD     = 173120;  // OCAP i
    const size_t OFF_OROW   = OFF_OD + OCAP;            // OCAP*16 f
    const size_t OFF_BUCKET = OFF_OROW + (size_t)OCAP * 16;  // N*CAP*16 f
    const size_t NEED_BUCKET = (OFF_BUCKET + (size_t)N_NODES * CAP * OUT_DIM) * 4;

    // CSR path
    const size_t OFF_BASE   = 173104;  // 50001 i (+15 pad)
    const size_t OFF_CURSOR = 223120;  // 50000 i
    const size_t OFF_PART   = 273120;  // 256 i
    const size_t OFF_PBASE  = 273376;  // 256 i
    const size_t OFF_MSG    = 273632;  // 12.8M f
    const size_t NEED_CSR   = (OFF_MSG + (size_t)N_EDGES * OUT_DIM) * 4;

    float* wsf  = (float*)d_ws;
    float* Wrel = wsf + OFF_WREL;
    float* avec = wsf + OFF_AVEC;
    float2* s13 = (float2*)(wsf + OFF_S13);
    int* cnt    = (int*)(wsf + OFF_CNT);

    if (ws_size >= NEED_BUCKET) {
        int* ocount   = (int*)(wsf + OFF_OCNT);
        int* od       = (int*)(wsf + OFF_OD);
        float* orow   = wsf + OFF_OROW;
        float* bucket = wsf + OFF_BUCKET;

        setup_kernel<<<PREP_BLOCKS + DOTS_BLOCKS + ZERO_BLOCKS + 1, 256, 0, stream>>>(
            Ws, Wa, weight, w_comp, h, Wrel, avec, s13, cnt, ocount);
        compute_bucket_kernel<<<N_EDGES / 128, 256, 0, stream>>>(
            h, he, src, dst, rel, Wrel, avec, s13, cnt, bucket, ocount, od, orow);
        reduce_bucket_kernel<<<(N_NODES * 4 + 255) / 256, 256, 0, stream>>>(
            bucket, cnt, hout);
        overflow_kernel<<<32, 256, 0, stream>>>(ocount, od, orow, hout);
    } else if (ws_size >= NEED_CSR) {
        int* csbase = (int*)(wsf + OFF_BASE);
        int* cursor = (int*)(wsf + OFF_CURSOR);
        int* part   = (int*)(wsf + OFF_PART);
        int* pbase  = (int*)(wsf + OFF_PBASE);
        float* msg  = wsf + OFF_MSG;

        {
            int total = N_RELS * IN_DIM * OUT_DIM + 48;
            prep_kernel<<<(total + 255) / 256, 256, 0, stream>>>(Ws, Wa, weight, w_comp, Wrel, avec);
        }
        hipMemsetAsync(cnt, 0, N_NODES * sizeof(int), stream);
        dots_count_kernel<<<DOTS_BLOCKS + COUNT_BLOCKS, 256, 0, stream>>>(h, avec, s13, dst, cnt);
        scanA_kernel<<<SCAN_BLOCKS, 256, 0, stream>>>(cnt, part);
        scanB_kernel<<<1, 256, 0, stream>>>(part, pbase, csbase);
        scanC_kernel<<<SCAN_BLOCKS, 256, 0, stream>>>(cnt, pbase, csbase, cursor);
        compute_csr_kernel<<<(N_EDGES * 4 + 255) / 256, 256, 0, stream>>>(
            h, he, src, dst, rel, Wrel, avec, s13, cursor, msg);
        reduce_csr_kernel<<<(N_NODES * OUT_DIM + 255) / 256, 256, 0, stream>>>(msg, csbase, hout);
    }
}

// Round 8
// 197.161 us; speedup vs baseline: 1.2991x; 1.0256x over previous
//
#include <hip/hip_runtime.h>

#define N_NODES 50000
#define N_EDGES 800000
#define IN_DIM 16
#define OUT_DIM 16
#define N_RELS 90
#define N_BASES 30

#define CAP 24          // bucket rows per node (avg deg 16; P(deg>24) ~ 2%)
#define LDS_STRIDE 260  // 256 + 4 pad: bank = 4(r+q)+16i mod 32 -> ~2-way, free
#define EDGES_PER_BLK 3125  // 256 blocks x 3125 = 800000, contiguous he stream

#define PREP_BLOCKS 91  // 91*256 = 23296 >= 23088
#define DOTS_BLOCKS 196 // 196*256 = 50176 >= 50000
#define ZERO_BLOCKS 196

__device__ __forceinline__ float4 shfl_xor4(float4 v, int m) {
    float4 r;
    r.x = __shfl_xor(v.x, m); r.y = __shfl_xor(v.y, m);
    r.z = __shfl_xor(v.z, m); r.w = __shfl_xor(v.w, m);
    return r;
}

// ---------------------------------------------------------------------------
// Setup: [0,91) prep Wrel+avec; [91,287) node dots; [287,483) zero cnt.
// ---------------------------------------------------------------------------
__global__ __launch_bounds__(256) void setup_kernel(
    const float* __restrict__ Ws,
    const float* __restrict__ Wa,
    const float* __restrict__ weight,
    const float* __restrict__ w_comp,
    const float* __restrict__ h,
    float* __restrict__ Wrel,
    float* __restrict__ avec,
    float2* __restrict__ s13,
    int* __restrict__ cnt)
{
    int b = blockIdx.x;
    if (b < PREP_BLOCKS) {
        int f = b * 256 + threadIdx.x;
        if (f < N_RELS * IN_DIM * OUT_DIM) {
            int a   = f / (N_RELS * OUT_DIM);
            int rem = f % (N_RELS * OUT_DIM);
            int r   = rem / OUT_DIM;
            int o   = rem % OUT_DIM;
            float acc = 0.f;
            #pragma unroll
            for (int bb = 0; bb < N_BASES; ++bb)
                acc += w_comp[r * N_BASES + bb] * weight[a * (N_BASES * OUT_DIM) + bb * OUT_DIM + o];
            Wrel[f] = acc;
        } else if (f < N_RELS * IN_DIM * OUT_DIM + 48) {
            int g = f - N_RELS * IN_DIM * OUT_DIM;
            int k = g / IN_DIM;
            int i = g % IN_DIM;
            float acc = 0.f;
            #pragma unroll
            for (int o = 0; o < OUT_DIM; ++o)
                acc += Wa[k * OUT_DIM + o] * Ws[o * IN_DIM + i];
            avec[g] = acc;
        }
    } else if (b < PREP_BLOCKS + DOTS_BLOCKS) {
        __shared__ float la[48];
        if (threadIdx.x < 48) {
            int k = threadIdx.x / IN_DIM;
            int i = threadIdx.x % IN_DIM;
            float acc = 0.f;
            #pragma unroll
            for (int o = 0; o < OUT_DIM; ++o)
                acc += Wa[k * OUT_DIM + o] * Ws[o * IN_DIM + i];
            la[threadIdx.x] = acc;
        }
        __syncthreads();
        int n = (b - PREP_BLOCKS) * 256 + threadIdx.x;
        if (n >= N_NODES) return;
        const float4* p = (const float4*)(h + (size_t)n * IN_DIM);
        float d1 = 0.f, d3 = 0.f;
        #pragma unroll
        for (int i = 0; i < 4; ++i) {
            float4 v = p[i];
            d1 += v.x * la[4*i+0] + v.y * la[4*i+1] + v.z * la[4*i+2] + v.w * la[4*i+3];
            d3 += v.x * la[32+4*i+0] + v.y * la[32+4*i+1] + v.z * la[32+4*i+2] + v.w * la[32+4*i+3];
        }
        s13[n] = make_float2(d1, d3);
    } else {
        int n = (b - PREP_BLOCKS - DOTS_BLOCKS) * 256 + threadIdx.x;
        if (n < N_NODES) cnt[n] = 0;
    }
}

// ---------------------------------------------------------------------------
// Edge compute: full Wrel in LDS (padded), 1024 threads/block, block owns a
// contiguous 3125-edge range (coalesced he stream), 4 lanes/edge, one-edge
// prefetch. Bucket stores; overflow -> direct atomicAdd into hout (zeroed).
// ---------------------------------------------------------------------------
__global__ __launch_bounds__(1024) void compute_lds_kernel(
    const float* __restrict__ h,
    const float* __restrict__ he,
    const int* __restrict__ src,
    const int* __restrict__ dst,
    const int* __restrict__ rel,
    const float* __restrict__ Wrel,
    const float* __restrict__ avec,
    const float2* __restrict__ s13,
    int* __restrict__ cnt,
    float* __restrict__ bucket,   // [N_NODES*CAP*16]
    float* __restrict__ hout)     // overflow target (pre-zeroed)
{
    extern __shared__ float lw[];   // [N_RELS * LDS_STRIDE] = 93600 B

    // ---- stage Wrel -> LDS (padded stride), coalesced float4 ----
    for (int j = threadIdx.x; j < N_RELS * 64; j += 1024) {
        int r = j >> 6;          // 64 float4 per relation
        int w = j & 63;
        float4 v = ((const float4*)Wrel)[r * 64 + w];
        *(float4*)(lw + r * LDS_STRIDE + w * 4) = v;
    }
    __syncthreads();

    const int t = threadIdx.x;
    const int q = t & 3;
    const int grp = t >> 2;                 // 0..255
    const int lbase = (t & 63) & ~3;
    const int ebeg = blockIdx.x * EDGES_PER_BLK;
    const int eend = ebeg + EDGES_PER_BLK;

    float4 av = *(const float4*)(avec + 16 + 4 * q);

    // ---- prologue: load first edge's operands ----
    int e = ebeg + grp;
    int s = 0, d = 0, r = 0;
    float4 heq = {0,0,0,0}, hq = {0,0,0,0};
    float2 svs = {0,0}, svd = {0,0};
    if (e < eend) {
        s = src[e]; d = dst[e]; r = rel[e];
        heq = *(const float4*)(he + (size_t)e * IN_DIM + q * 4);
        hq  = *(const float4*)(h  + (size_t)s * IN_DIM + q * 4);
        svs = s13[s]; svd = s13[d];
    }

    for (; e < eend; e += 256) {
        // ---- prefetch next edge while current computes ----
        int en = e + 256;
        int sn = 0, dn = 0, rn = 0;
        float4 heqn = {0,0,0,0}, hqn = {0,0,0,0};
        float2 svsn = {0,0}, svdn = {0,0};
        if (en < eend) {
            sn = src[en]; dn = dst[en]; rn = rel[en];
            heqn = *(const float4*)(he + (size_t)en * IN_DIM + q * 4);
            hqn  = *(const float4*)(h  + (size_t)sn * IN_DIM + q * 4);
            svsn = s13[sn]; svdn = s13[dn];
        }

        // ---- claim bucket slot (lane 0 of group), broadcast ----
        int slot = 0;
        if (q == 0) slot = atomicAdd(&cnt[d], 1);
        slot = __shfl(slot, lbase);

        // ---- score ----
        float pd = heq.x * av.x + heq.y * av.y + heq.z * av.z + heq.w * av.w;
        pd += __shfl_xor(pd, 1);
        pd += __shfl_xor(pd, 2);
        float score = svs.x + svd.y + pd;

        // ---- allgather h[src] row across the 4 lanes ----
        float4 o1 = shfl_xor4(hq, 1);
        float4 o2 = shfl_xor4(hq, 2);
        float4 o3 = shfl_xor4(o1, 2);
        bool q0 = (q == 0), q1 = (q == 1), q2 = (q == 2);
        float4 row0 = q0 ? hq : q1 ? o1 : q2 ? o2 : o3;
        float4 row1 = q0 ? o1 : q1 ? hq : q2 ? o3 : o2;
        float4 row2 = q0 ? o2 : q1 ? o3 : q2 ? hq : o1;
        float4 row3 = q0 ? o3 : q1 ? o2 : q2 ? o1 : hq;
        float hs[16] = {row0.x,row0.y,row0.z,row0.w, row1.x,row1.y,row1.z,row1.w,
                        row2.x,row2.y,row2.z,row2.w, row3.x,row3.y,row3.z,row3.w};

        // ---- matvec from LDS: lane's output quarter ----
        const float* wb = lw + (size_t)r * LDS_STRIDE + q * 4;
        float4 acc = {0.f, 0.f, 0.f, 0.f};
        #pragma unroll
        for (int i = 0; i < 16; ++i) {
            float4 w = *(const float4*)(wb + i * 16);
            float hv = hs[i];
            acc.x += hv * w.x; acc.y += hv * w.y; acc.z += hv * w.z; acc.w += hv * w.w;
        }
        acc.x *= score; acc.y *= score; acc.z *= score; acc.w *= score;

        // ---- store: bucket row, or direct atomics for rare overflow ----
        if (slot < CAP) {
            *(float4*)(bucket + ((size_t)d * CAP + slot) * OUT_DIM + q * 4) = acc;
        } else {
            float* outp = hout + (size_t)d * OUT_DIM + q * 4;
            atomicAdd(outp + 0, acc.x);
            atomicAdd(outp + 1, acc.y);
            atomicAdd(outp + 2, acc.z);
            atomicAdd(outp + 3, acc.w);
        }

        // ---- rotate prefetched operands in ----
        s = sn; d = dn; r = rn; heq = heqn; hq = hqn; svs = svsn; svd = svdn;
    }
}

// ---------------------------------------------------------------------------
// Reduce: 4 lanes/node, float4 reads. Plain store for deg<=CAP (no overflow
// touched hout[n]); atomicAdd for deg>CAP nodes (hout holds overflow part).
// ---------------------------------------------------------------------------
__global__ __launch_bounds__(256) void reduce_bucket_kernel(
    const float* __restrict__ bucket,
    const int* __restrict__ cnt,
    float* __restrict__ hout)
{
    int tid = blockIdx.x * 256 + threadIdx.x;
    int n = tid >> 2;
    int q = tid & 3;
    if (n >= N_NODES) return;

    int deg = cnt[n];
    int m = deg > CAP ? CAP : deg;
    const float4* bp = (const float4*)(bucket + (size_t)n * CAP * OUT_DIM) + q;
    float4 acc = {0.f, 0.f, 0.f, 0.f};
    for (int j = 0; j < m; ++j) {
        float4 v = bp[j * 4];
        acc.x += v.x; acc.y += v.y; acc.z += v.z; acc.w += v.w;
    }
    if (deg <= CAP) {
        *(float4*)(hout + (size_t)n * OUT_DIM + q * 4) = acc;
    } else {
        float* outp = hout + (size_t)n * OUT_DIM + q * 4;
        atomicAdd(outp + 0, acc.x);
        atomicAdd(outp + 1, acc.y);
        atomicAdd(outp + 2, acc.z);
        atomicAdd(outp + 3, acc.w);
    }
}

// ===========================================================================
// Fallback (ws too small): direct atomic scatter (known-correct).
// ===========================================================================
__global__ __launch_bounds__(256) void prep_kernel(
    const float* __restrict__ Ws, const float* __restrict__ Wa,
    const float* __restrict__ weight, const float* __restrict__ w_comp,
    float* __restrict__ Wrel, float* __restrict__ avec)
{
    int f = blockIdx.x * blockDim.x + threadIdx.x;
    if (f < N_RELS * IN_DIM * OUT_DIM) {
        int a   = f / (N_RELS * OUT_DIM);
        int rem = f % (N_RELS * OUT_DIM);
        int r   = rem / OUT_DIM;
        int o   = rem % OUT_DIM;
        float acc = 0.f;
        #pragma unroll
        for (int b = 0; b < N_BASES; ++b)
            acc += w_comp[r * N_BASES + b] * weight[a * (N_BASES * OUT_DIM) + b * OUT_DIM + o];
        Wrel[f] = acc;
    } else if (f < N_RELS * IN_DIM * OUT_DIM + 48) {
        int g = f - N_RELS * IN_DIM * OUT_DIM;
        int k = g / IN_DIM;
        int i = g % IN_DIM;
        float acc = 0.f;
        #pragma unroll
        for (int o = 0; o < OUT_DIM; ++o)
            acc += Wa[k * OUT_DIM + o] * Ws[o * IN_DIM + i];
        avec[g] = acc;
    }
}

__global__ __launch_bounds__(256) void edge_atomic_kernel(
    const float* __restrict__ h,
    const float* __restrict__ he,
    const int* __restrict__ src,
    const int* __restrict__ dst,
    const int* __restrict__ rel,
    const float* __restrict__ Wrel,
    const float* __restrict__ avec,
    float* __restrict__ hout)
{
    int e = blockIdx.x * blockDim.x + threadIdx.x;
    if (e >= N_EDGES) return;
    int s = src[e], d = dst[e], r = rel[e];
    float hs[IN_DIM];
    const float4* p = (const float4*)(h + (size_t)s * IN_DIM);
    #pragma unroll
    for (int i = 0; i < 4; ++i) {
        float4 v = p[i];
        hs[4*i+0] = v.x; hs[4*i+1] = v.y; hs[4*i+2] = v.z; hs[4*i+3] = v.w;
    }
    float score = 0.f;
    #pragma unroll
    for (int i = 0; i < IN_DIM; ++i) score += hs[i] * avec[i];
    const float4* qe = (const float4*)(he + (size_t)e * IN_DIM);
    #pragma unroll
    for (int i = 0; i < 4; ++i) {
        float4 v = qe[i];
        score += v.x * avec[16+4*i] + v.y * avec[17+4*i] + v.z * avec[18+4*i] + v.w * avec[19+4*i];
    }
    const float4* pd = (const float4*)(h + (size_t)d * IN_DIM);
    #pragma unroll
    for (int i = 0; i < 4; ++i) {
        float4 v = pd[i];
        score += v.x * avec[32+4*i] + v.y * avec[33+4*i] + v.z * avec[34+4*i] + v.w * avec[35+4*i];
    }
    float acc[OUT_DIM];
    #pragma unroll
    for (int o = 0; o < OUT_DIM; ++o) acc[o] = 0.f;
    const float* W = Wrel + (size_t)r * 256;
    #pragma unroll
    for (int i = 0; i < IN_DIM; ++i) {
        float hv = hs[i];
        #pragma unroll
        for (int o = 0; o < OUT_DIM; ++o) acc[o] += hv * W[i * OUT_DIM + o];
    }
    float* outp = hout + (size_t)d * OUT_DIM;
    #pragma unroll
    for (int o = 0; o < OUT_DIM; ++o) atomicAdd(outp + o, acc[o] * score);
}

extern "C" void kernel_launch(void* const* d_in, const int* in_sizes, int n_in,
                              void* d_out, int out_size, void* d_ws, size_t ws_size,
                              hipStream_t stream) {
    const float* h      = (const float*)d_in[0];
    const float* he     = (const float*)d_in[1];
    const float* Ws     = (const float*)d_in[2];
    const float* Wa     = (const float*)d_in[3];
    const float* weight = (const float*)d_in[4];
    const float* w_comp = (const float*)d_in[5];
    const int*   src    = (const int*)d_in[6];
    const int*   dst    = (const int*)d_in[7];
    const int*   rel    = (const int*)d_in[8];
    float* hout = (float*)d_out;

    // ws layout (float offsets)
    const size_t OFF_WREL   = 0;         // 23040 f
    const size_t OFF_AVEC   = 23040;     // 48 f (+16 pad)
    const size_t OFF_S13    = 23104;     // 100000 f
    const size_t OFF_CNT    = 123104;    // 50000 i
    const size_t OFF_BUCKET = 173104;    // N*CAP*16 f (16-f aligned)
    const size_t NEED_BUCKET = (OFF_BUCKET + (size_t)N_NODES * CAP * OUT_DIM) * 4;

    float* wsf  = (float*)d_ws;
    float* Wrel = wsf + OFF_WREL;
    float* avec = wsf + OFF_AVEC;
    float2* s13 = (float2*)(wsf + OFF_S13);
    int* cnt    = (int*)(wsf + OFF_CNT);

    hipMemsetAsync(d_out, 0, (size_t)out_size * sizeof(float), stream);

    if (ws_size >= NEED_BUCKET) {
        float* bucket = wsf + OFF_BUCKET;

        setup_kernel<<<PREP_BLOCKS + DOTS_BLOCKS + ZERO_BLOCKS, 256, 0, stream>>>(
            Ws, Wa, weight, w_comp, h, Wrel, avec, s13, cnt);
        compute_lds_kernel<<<N_EDGES / EDGES_PER_BLK, 1024,
                             N_RELS * LDS_STRIDE * sizeof(float), stream>>>(
            h, he, src, dst, rel, Wrel, avec, s13, cnt, bucket, hout);
        reduce_bucket_kernel<<<(N_NODES * 4 + 255) / 256, 256, 0, stream>>>(
            bucket, cnt, hout);
    } else {
        int total = N_RELS * IN_DIM * OUT_DIM + 48;
        prep_kernel<<<(total + 255) / 256, 256, 0, stream>>>(Ws, Wa, weight, w_comp, Wrel, avec);
        edge_atomic_kernel<<<(N_EDGES + 255) / 256, 256, 0, stream>>>(
            h, he, src, dst, rel, Wrel, avec, hout);
    }
}

// Round 9
// 195.636 us; speedup vs baseline: 1.3093x; 1.0078x over previous
//
#include <hip/hip_runtime.h>

#define N_NODES 50000
#define N_EDGES 800000
#define IN_DIM 16
#define OUT_DIM 16
#define N_RELS 90
#define N_BASES 30

#define CAP 24          // bucket rows per node (avg deg 16; P(deg>24) ~ 2%)
#define LDS_STRIDE 260  // 256 + 4 pad: bank = 4(r+q)+16i mod 32 -> ~2-way, free
#define EDGES_PER_BLK 3125  // 256 blocks x 3125 = 800000, contiguous he stream

#define PREP_BLOCKS 91  // 91*256 = 23296 >= 23088
#define DOTS_BLOCKS 196 // 196*256 = 50176 >= 50000
#define ZERO_BLOCKS 196

__device__ __forceinline__ float4 shfl_xor4(float4 v, int m) {
    float4 r;
    r.x = __shfl_xor(v.x, m); r.y = __shfl_xor(v.y, m);
    r.z = __shfl_xor(v.z, m); r.w = __shfl_xor(v.w, m);
    return r;
}

// ---------------------------------------------------------------------------
// Setup: [0,91) prep Wrel+avec; [91,287) node dots; [287,483) zero cnt.
// ---------------------------------------------------------------------------
__global__ __launch_bounds__(256) void setup_kernel(
    const float* __restrict__ Ws,
    const float* __restrict__ Wa,
    const float* __restrict__ weight,
    const float* __restrict__ w_comp,
    const float* __restrict__ h,
    float* __restrict__ Wrel,
    float* __restrict__ avec,
    float2* __restrict__ s13,
    int* __restrict__ cnt)
{
    int b = blockIdx.x;
    if (b < PREP_BLOCKS) {
        int f = b * 256 + threadIdx.x;
        if (f < N_RELS * IN_DIM * OUT_DIM) {
            int a   = f / (N_RELS * OUT_DIM);
            int rem = f % (N_RELS * OUT_DIM);
            int r   = rem / OUT_DIM;
            int o   = rem % OUT_DIM;
            float acc = 0.f;
            #pragma unroll
            for (int bb = 0; bb < N_BASES; ++bb)
                acc += w_comp[r * N_BASES + bb] * weight[a * (N_BASES * OUT_DIM) + bb * OUT_DIM + o];
            Wrel[f] = acc;
        } else if (f < N_RELS * IN_DIM * OUT_DIM + 48) {
            int g = f - N_RELS * IN_DIM * OUT_DIM;
            int k = g / IN_DIM;
            int i = g % IN_DIM;
            float acc = 0.f;
            #pragma unroll
            for (int o = 0; o < OUT_DIM; ++o)
                acc += Wa[k * OUT_DIM + o] * Ws[o * IN_DIM + i];
            avec[g] = acc;
        }
    } else if (b < PREP_BLOCKS + DOTS_BLOCKS) {
        __shared__ float la[48];
        if (threadIdx.x < 48) {
            int k = threadIdx.x / IN_DIM;
            int i = threadIdx.x % IN_DIM;
            float acc = 0.f;
            #pragma unroll
            for (int o = 0; o < OUT_DIM; ++o)
                acc += Wa[k * OUT_DIM + o] * Ws[o * IN_DIM + i];
            la[threadIdx.x] = acc;
        }
        __syncthreads();
        int n = (b - PREP_BLOCKS) * 256 + threadIdx.x;
        if (n >= N_NODES) return;
        const float4* p = (const float4*)(h + (size_t)n * IN_DIM);
        float d1 = 0.f, d3 = 0.f;
        #pragma unroll
        for (int i = 0; i < 4; ++i) {
            float4 v = p[i];
            d1 += v.x * la[4*i+0] + v.y * la[4*i+1] + v.z * la[4*i+2] + v.w * la[4*i+3];
            d3 += v.x * la[32+4*i+0] + v.y * la[32+4*i+1] + v.z * la[32+4*i+2] + v.w * la[32+4*i+3];
        }
        s13[n] = make_float2(d1, d3);
    } else {
        int n = (b - PREP_BLOCKS - DOTS_BLOCKS) * 256 + threadIdx.x;
        if (n < N_NODES) cnt[n] = 0;
    }
}

// ---------------------------------------------------------------------------
// Edge compute: Wrel in LDS, 1024 threads/block, contiguous 3125-edge range,
// 4 lanes/edge, DEPTH-3 software pipeline:
//   iter k: [A] idx loads for e+512, [B] data loads + slot atomic for e+256,
//           [C] process e.
// Bucket stores; overflow -> direct atomicAdd into pre-zeroed hout.
// ---------------------------------------------------------------------------
__global__ __launch_bounds__(1024) void compute_lds_kernel(
    const float* __restrict__ h,
    const float* __restrict__ he,
    const int* __restrict__ src,
    const int* __restrict__ dst,
    const int* __restrict__ rel,
    const float* __restrict__ Wrel,
    const float* __restrict__ avec,
    const float2* __restrict__ s13,
    int* __restrict__ cnt,
    float* __restrict__ bucket,   // [N_NODES*CAP*16]
    float* __restrict__ hout)     // overflow target (pre-zeroed)
{
    extern __shared__ float lw[];   // [N_RELS * LDS_STRIDE]

    // ---- stage Wrel -> LDS (padded stride), coalesced float4 ----
    for (int j = threadIdx.x; j < N_RELS * 64; j += 1024) {
        int r = j >> 6;
        int w = j & 63;
        float4 v = ((const float4*)Wrel)[r * 64 + w];
        *(float4*)(lw + r * LDS_STRIDE + w * 4) = v;
    }
    __syncthreads();

    const int t = threadIdx.x;
    const int q = t & 3;
    const int grp = t >> 2;                 // 0..255
    const int lbase = (t & 63) & ~3;
    const int ebeg = blockIdx.x * EDGES_PER_BLK;
    const int eend = ebeg + EDGES_PER_BLK;  // exact: 800000 % 3125 == 0

    float4 av = *(const float4*)(avec + 16 + 4 * q);

    // ---- pipeline registers ----
    int e0 = ebeg + grp;         // process stage
    int e1 = e0 + 256;           // data-load stage
    int e2 = e0 + 512;           // idx-load stage

    // prologue: idx for e0, e1
    int s0 = src[e0], d0 = dst[e0], r0 = rel[e0];
    int s1 = 0, d1 = 0, r1 = 0;
    if (e1 < eend) { s1 = src[e1]; d1 = dst[e1]; r1 = rel[e1]; }

    // prologue: data + atomic for e0
    float4 heq0 = *(const float4*)(he + (size_t)e0 * IN_DIM + q * 4);
    float4 hq0  = *(const float4*)(h  + (size_t)s0 * IN_DIM + q * 4);
    float2 svs0 = s13[s0], svd0 = s13[d0];
    int slot0 = 0;
    if (q == 0) slot0 = atomicAdd(&cnt[d0], 1);

    for (; e0 < eend; ) {
        // ---- [A] idx loads for e2 ----
        int s2 = 0, d2 = 0, r2 = 0;
        if (e2 < eend) { s2 = src[e2]; d2 = dst[e2]; r2 = rel[e2]; }

        // ---- [B] data loads + slot atomic for e1 ----
        float4 heq1 = {0,0,0,0}, hq1 = {0,0,0,0};
        float2 svs1 = {0,0}, svd1 = {0,0};
        int slot1 = 0;
        if (e1 < eend) {
            heq1 = *(const float4*)(he + (size_t)e1 * IN_DIM + q * 4);
            hq1  = *(const float4*)(h  + (size_t)s1 * IN_DIM + q * 4);
            svs1 = s13[s1]; svd1 = s13[d1];
            if (q == 0) slot1 = atomicAdd(&cnt[d1], 1);
        }

        // ---- [C] process e0 ----
        int slot = __shfl(slot0, lbase);

        float pd = heq0.x * av.x + heq0.y * av.y + heq0.z * av.z + heq0.w * av.w;
        pd += __shfl_xor(pd, 1);
        pd += __shfl_xor(pd, 2);
        float score = svs0.x + svd0.y + pd;

        float4 o1 = shfl_xor4(hq0, 1);
        float4 o2 = shfl_xor4(hq0, 2);
        float4 o3 = shfl_xor4(o1, 2);
        bool q0 = (q == 0), q1 = (q == 1), q2 = (q == 2);
        float4 row0 = q0 ? hq0 : q1 ? o1 : q2 ? o2 : o3;
        float4 row1 = q0 ? o1 : q1 ? hq0 : q2 ? o3 : o2;
        float4 row2 = q0 ? o2 : q1 ? o3 : q2 ? hq0 : o1;
        float4 row3 = q0 ? o3 : q1 ? o2 : q2 ? o1 : hq0;
        float hs[16] = {row0.x,row0.y,row0.z,row0.w, row1.x,row1.y,row1.z,row1.w,
                        row2.x,row2.y,row2.z,row2.w, row3.x,row3.y,row3.z,row3.w};

        const float* wb = lw + (size_t)r0 * LDS_STRIDE + q * 4;
        float4 acc = {0.f, 0.f, 0.f, 0.f};
        #pragma unroll
        for (int i = 0; i < 16; ++i) {
            float4 w = *(const float4*)(wb + i * 16);
            float hv = hs[i];
            acc.x += hv * w.x; acc.y += hv * w.y; acc.z += hv * w.z; acc.w += hv * w.w;
        }
        acc.x *= score; acc.y *= score; acc.z *= score; acc.w *= score;

        if (slot < CAP) {
            *(float4*)(bucket + ((size_t)d0 * CAP + slot) * OUT_DIM + q * 4) = acc;
        } else {
            float* outp = hout + (size_t)d0 * OUT_DIM + q * 4;
            atomicAdd(outp + 0, acc.x);
            atomicAdd(outp + 1, acc.y);
            atomicAdd(outp + 2, acc.z);
            atomicAdd(outp + 3, acc.w);
        }

        // ---- rotate ----
        e0 = e1; e1 = e2; e2 += 256;
        s0 = s1; d0 = d1; r0 = r1;
        s1 = s2; d1 = d2; r1 = r2;
        heq0 = heq1; hq0 = hq1; svs0 = svs1; svd0 = svd1;
        slot0 = slot1;
    }
}

// ---------------------------------------------------------------------------
// Reduce: 16 lanes/node (quarter q x stream p), 4 parallel j-streams, 2-step
// butterfly. Plain store for deg<=CAP, atomicAdd for deg>CAP (overflow part
// already accumulated in hout).
// ---------------------------------------------------------------------------
__global__ __launch_bounds__(256) void reduce_bucket_kernel(
    const float* __restrict__ bucket,
    const int* __restrict__ cnt,
    float* __restrict__ hout)
{
    int tid = blockIdx.x * 256 + threadIdx.x;
    int n = tid >> 4;
    int l = tid & 15;
    int q = l & 3;
    int p = l >> 2;      // 0..3: j-stream
    if (n >= N_NODES) return;

    int deg = cnt[n];
    int m = deg > CAP ? CAP : deg;
    const float4* bp = (const float4*)(bucket + (size_t)n * CAP * OUT_DIM) + q;
    float4 acc = {0.f, 0.f, 0.f, 0.f};
    for (int j = p; j < m; j += 4) {
        float4 v = bp[j * 4];
        acc.x += v.x; acc.y += v.y; acc.z += v.z; acc.w += v.w;
    }
    // combine the 4 streams (lanes differing in bits 2,3)
    acc.x += __shfl_xor(acc.x, 4); acc.y += __shfl_xor(acc.y, 4);
    acc.z += __shfl_xor(acc.z, 4); acc.w += __shfl_xor(acc.w, 4);
    acc.x += __shfl_xor(acc.x, 8); acc.y += __shfl_xor(acc.y, 8);
    acc.z += __shfl_xor(acc.z, 8); acc.w += __shfl_xor(acc.w, 8);

    if (p == 0) {
        if (deg <= CAP) {
            *(float4*)(hout + (size_t)n * OUT_DIM + q * 4) = acc;
        } else {
            float* outp = hout + (size_t)n * OUT_DIM + q * 4;
            atomicAdd(outp + 0, acc.x);
            atomicAdd(outp + 1, acc.y);
            atomicAdd(outp + 2, acc.z);
            atomicAdd(outp + 3, acc.w);
        }
    }
}

// ===========================================================================
// Fallback (ws too small): direct atomic scatter (known-correct).
// ===========================================================================
__global__ __launch_bounds__(256) void prep_kernel(
    const float* __restrict__ Ws, const float* __restrict__ Wa,
    const float* __restrict__ weight, const float* __restrict__ w_comp,
    float* __restrict__ Wrel, float* __restrict__ avec)
{
    int f = blockIdx.x * blockDim.x + threadIdx.x;
    if (f < N_RELS * IN_DIM * OUT_DIM) {
        int a   = f / (N_RELS * OUT_DIM);
        int rem = f % (N_RELS * OUT_DIM);
        int r   = rem / OUT_DIM;
        int o   = rem % OUT_DIM;
        float acc = 0.f;
        #pragma unroll
        for (int b = 0; b < N_BASES; ++b)
            acc += w_comp[r * N_BASES + b] * weight[a * (N_BASES * OUT_DIM) + b * OUT_DIM + o];
        Wrel[f] = acc;
    } else if (f < N_RELS * IN_DIM * OUT_DIM + 48) {
        int g = f - N_RELS * IN_DIM * OUT_DIM;
        int k = g / IN_DIM;
        int i = g % IN_DIM;
        float acc = 0.f;
        #pragma unroll
        for (int o = 0; o < OUT_DIM; ++o)
            acc += Wa[k * OUT_DIM + o] * Ws[o * IN_DIM + i];
        avec[g] = acc;
    }
}

__global__ __launch_bounds__(256) void edge_atomic_kernel(
    const float* __restrict__ h,
    const float* __restrict__ he,
    const int* __restrict__ src,
    const int* __restrict__ dst,
    const int* __restrict__ rel,
    const float* __restrict__ Wrel,
    const float* __restrict__ avec,
    float* __restrict__ hout)
{
    int e = blockIdx.x * blockDim.x + threadIdx.x;
    if (e >= N_EDGES) return;
    int s = src[e], d = dst[e], r = rel[e];
    float hs[IN_DIM];
    const float4* p = (const float4*)(h + (size_t)s * IN_DIM);
    #pragma unroll
    for (int i = 0; i < 4; ++i) {
        float4 v = p[i];
        hs[4*i+0] = v.x; hs[4*i+1] = v.y; hs[4*i+2] = v.z; hs[4*i+3] = v.w;
    }
    float score = 0.f;
    #pragma unroll
    for (int i = 0; i < IN_DIM; ++i) score += hs[i] * avec[i];
    const float4* qe = (const float4*)(he + (size_t)e * IN_DIM);
    #pragma unroll
    for (int i = 0; i < 4; ++i) {
        float4 v = qe[i];
        score += v.x * avec[16+4*i] + v.y * avec[17+4*i] + v.z * avec[18+4*i] + v.w * avec[19+4*i];
    }
    const float4* pd = (const float4*)(h + (size_t)d * IN_DIM);
    #pragma unroll
    for (int i = 0; i < 4; ++i) {
        float4 v = pd[i];
        score += v.x * avec[32+4*i] + v.y * avec[33+4*i] + v.z * avec[34+4*i] + v.w * avec[35+4*i];
    }
    float acc[OUT_DIM];
    #pragma unroll
    for (int o = 0; o < OUT_DIM; ++o) acc[o] = 0.f;
    const float* W = Wrel + (size_t)r * 256;
    #pragma unroll
    for (int i = 0; i < IN_DIM; ++i) {
        float hv = hs[i];
        #pragma unroll
        for (int o = 0; o < OUT_DIM; ++o) acc[o] += hv * W[i * OUT_DIM + o];
    }
    float* outp = hout + (size_t)d * OUT_DIM;
    #pragma unroll
    for (int o = 0; o < OUT_DIM; ++o) atomicAdd(outp + o, acc[o] * score);
}

extern "C" void kernel_launch(void* const* d_in, const int* in_sizes, int n_in,
                              void* d_out, int out_size, void* d_ws, size_t ws_size,
                              hipStream_t stream) {
    const float* h      = (const float*)d_in[0];
    const float* he     = (const float*)d_in[1];
    const float* Ws     = (const float*)d_in[2];
    const float* Wa     = (const float*)d_in[3];
    const float* weight = (const float*)d_in[4];
    const float* w_comp = (const float*)d_in[5];
    const int*   src    = (const int*)d_in[6];
    const int*   dst    = (const int*)d_in[7];
    const int*   rel    = (const int*)d_in[8];
    float* hout = (float*)d_out;

    // ws layout (float offsets)
    const size_t OFF_WREL   = 0;         // 23040 f
    const size_t OFF_AVEC   = 23040;     // 48 f (+16 pad)
    const size_t OFF_S13    = 23104;     // 100000 f
    const size_t OFF_CNT    = 123104;    // 50000 i
    const size_t OFF_BUCKET = 173104;    // N*CAP*16 f (16-f aligned)
    const size_t NEED_BUCKET = (OFF_BUCKET + (size_t)N_NODES * CAP * OUT_DIM) * 4;

    float* wsf  = (float*)d_ws;
    float* Wrel = wsf + OFF_WREL;
    float* avec = wsf + OFF_AVEC;
    float2* s13 = (float2*)(wsf + OFF_S13);
    int* cnt    = (int*)(wsf + OFF_CNT);

    hipMemsetAsync(d_out, 0, (size_t)out_size * sizeof(float), stream);

    if (ws_size >= NEED_BUCKET) {
        float* bucket = wsf + OFF_BUCKET;

        setup_kernel<<<PREP_BLOCKS + DOTS_BLOCKS + ZERO_BLOCKS, 256, 0, stream>>>(
            Ws, Wa, weight, w_comp, h, Wrel, avec, s13, cnt);
        compute_lds_kernel<<<N_EDGES / EDGES_PER_BLK, 1024,
                             N_RELS * LDS_STRIDE * sizeof(float), stream>>>(
            h, he, src, dst, rel, Wrel, avec, s13, cnt, bucket, hout);
        reduce_bucket_kernel<<<(N_NODES * 16 + 255) / 256, 256, 0, stream>>>(
            bucket, cnt, hout);
    } else {
        int total = N_RELS * IN_DIM * OUT_DIM + 48;
        prep_kernel<<<(total + 255) / 256, 256, 0, stream>>>(Ws, Wa, weight, w_comp, Wrel, avec);
        edge_atomic_kernel<<<(N_EDGES + 255) / 256, 256, 0, stream>>>(
            h, he, src, dst, rel, Wrel, avec, hout);
    }
}

// Round 10
// 188.563 us; speedup vs baseline: 1.3584x; 1.0375x over previous
//
#include <hip/hip_runtime.h>

#define N_NODES 50000
#define N_EDGES 800000
#define IN_DIM 16
#define OUT_DIM 16
#define N_RELS 90
#define N_BASES 30

#define CAP 24          // bucket rows per node (avg deg 16; P(deg>24) ~ 2%)
#define LDS_STRIDE 260  // 256 + 4 pad: ~2-way LDS conflicts (free per m136)
#define EDGES_PER_BLK 3125  // 256 blocks x 3125 = 800000, contiguous he stream

#define PREP_BLOCKS 91   // 91*256 = 23296 >= 23088
#define DOTS_BLOCKS 196  // 196*256 = 50176 >= 50000
#define ZERO_BLOCKS 196
#define HZ_BLOCKS 782    // 782*256 float4 >= 200000 float4 (zero hout)

__device__ __forceinline__ float4 shfl_xor4(float4 v, int m) {
    float4 r;
    r.x = __shfl_xor(v.x, m); r.y = __shfl_xor(v.y, m);
    r.z = __shfl_xor(v.z, m); r.w = __shfl_xor(v.w, m);
    return r;
}

// ---------------------------------------------------------------------------
// Setup: [0,91) prep Wrel+avec; [91,287) node dots; [287,483) zero cnt;
// [483,1265) zero hout (replaces hipMemsetAsync dispatch).
// ---------------------------------------------------------------------------
__global__ __launch_bounds__(256) void setup_kernel(
    const float* __restrict__ Ws,
    const float* __restrict__ Wa,
    const float* __restrict__ weight,
    const float* __restrict__ w_comp,
    const float* __restrict__ h,
    float* __restrict__ Wrel,
    float* __restrict__ avec,
    float2* __restrict__ s13,
    int* __restrict__ cnt,
    float* __restrict__ hout)
{
    int b = blockIdx.x;
    if (b < PREP_BLOCKS) {
        int f = b * 256 + threadIdx.x;
        if (f < N_RELS * IN_DIM * OUT_DIM) {
            int a   = f / (N_RELS * OUT_DIM);
            int rem = f % (N_RELS * OUT_DIM);
            int r   = rem / OUT_DIM;
            int o   = rem % OUT_DIM;
            float acc = 0.f;
            #pragma unroll
            for (int bb = 0; bb < N_BASES; ++bb)
                acc += w_comp[r * N_BASES + bb] * weight[a * (N_BASES * OUT_DIM) + bb * OUT_DIM + o];
            Wrel[f] = acc;
        } else if (f < N_RELS * IN_DIM * OUT_DIM + 48) {
            int g = f - N_RELS * IN_DIM * OUT_DIM;
            int k = g / IN_DIM;
            int i = g % IN_DIM;
            float acc = 0.f;
            #pragma unroll
            for (int o = 0; o < OUT_DIM; ++o)
                acc += Wa[k * OUT_DIM + o] * Ws[o * IN_DIM + i];
            avec[g] = acc;
        }
    } else if (b < PREP_BLOCKS + DOTS_BLOCKS) {
        __shared__ float la[48];
        if (threadIdx.x < 48) {
            int k = threadIdx.x / IN_DIM;
            int i = threadIdx.x % IN_DIM;
            float acc = 0.f;
            #pragma unroll
            for (int o = 0; o < OUT_DIM; ++o)
                acc += Wa[k * OUT_DIM + o] * Ws[o * IN_DIM + i];
            la[threadIdx.x] = acc;
        }
        __syncthreads();
        int n = (b - PREP_BLOCKS) * 256 + threadIdx.x;
        if (n >= N_NODES) return;
        const float4* p = (const float4*)(h + (size_t)n * IN_DIM);
        float d1 = 0.f, d3 = 0.f;
        #pragma unroll
        for (int i = 0; i < 4; ++i) {
            float4 v = p[i];
            d1 += v.x * la[4*i+0] + v.y * la[4*i+1] + v.z * la[4*i+2] + v.w * la[4*i+3];
            d3 += v.x * la[32+4*i+0] + v.y * la[32+4*i+1] + v.z * la[32+4*i+2] + v.w * la[32+4*i+3];
        }
        s13[n] = make_float2(d1, d3);
    } else if (b < PREP_BLOCKS + DOTS_BLOCKS + ZERO_BLOCKS) {
        int n = (b - PREP_BLOCKS - DOTS_BLOCKS) * 256 + threadIdx.x;
        if (n < N_NODES) cnt[n] = 0;
    } else {
        int idx = (b - PREP_BLOCKS - DOTS_BLOCKS - ZERO_BLOCKS) * 256 + threadIdx.x;
        if (idx < N_NODES * OUT_DIM / 4) {
            float4 z = {0.f, 0.f, 0.f, 0.f};
            ((float4*)hout)[idx] = z;
        }
    }
}

// ---------------------------------------------------------------------------
// Edge compute: Wrel in LDS, 1024 threads/block, contiguous 3125-edge range,
// 4 lanes/edge, 4-EDGE BATCH per macro-iteration (loads-then-process, no
// register rotation -> compiler keeps ~4x loads in flight).
// Bucket stores; overflow -> direct atomicAdd into pre-zeroed hout.
// ---------------------------------------------------------------------------
__global__ __launch_bounds__(1024) void compute_lds_kernel(
    const float* __restrict__ h,
    const float* __restrict__ he,
    const int* __restrict__ src,
    const int* __restrict__ dst,
    const int* __restrict__ rel,
    const float* __restrict__ Wrel,
    const float* __restrict__ avec,
    const float2* __restrict__ s13,
    int* __restrict__ cnt,
    float* __restrict__ bucket,   // [N_NODES*CAP*16]
    float* __restrict__ hout)     // overflow target (pre-zeroed)
{
    extern __shared__ float lw[];   // [N_RELS * LDS_STRIDE]

    // ---- stage Wrel -> LDS (padded stride), coalesced float4 ----
    for (int j = threadIdx.x; j < N_RELS * 64; j += 1024) {
        int r = j >> 6;
        int w = j & 63;
        float4 v = ((const float4*)Wrel)[r * 64 + w];
        *(float4*)(lw + r * LDS_STRIDE + w * 4) = v;
    }
    __syncthreads();

    const int t = threadIdx.x;
    const int q = t & 3;
    const int grp = t >> 2;                 // 0..255
    const int lbase = (t & 63) & ~3;
    const int ebeg = blockIdx.x * EDGES_PER_BLK;
    const int eend = ebeg + EDGES_PER_BLK;

    float4 av = *(const float4*)(avec + 16 + 4 * q);

    for (int base = ebeg + grp; base < eend; base += 1024) {
        int e[4], s[4], d[4], r[4];
        bool val[4];

        // ---- [1] all idx loads (independent chains) ----
        #pragma unroll
        for (int k = 0; k < 4; ++k) {
            e[k] = base + k * 256;
            val[k] = (e[k] < eend);
            int ec = val[k] ? e[k] : ebeg;
            s[k] = src[ec]; d[k] = dst[ec]; r[k] = rel[ec];
        }

        // ---- [2] all data loads (4 independent gather chains) ----
        float4 heq[4], hq[4];
        float2 svs[4], svd[4];
        #pragma unroll
        for (int k = 0; k < 4; ++k) {
            int ec = val[k] ? e[k] : ebeg;
            heq[k] = *(const float4*)(he + (size_t)ec * IN_DIM + q * 4);
            hq[k]  = *(const float4*)(h  + (size_t)s[k] * IN_DIM + q * 4);
            svs[k] = s13[s[k]];
            svd[k] = s13[d[k]];
        }

        // ---- [3] all slot atomics ----
        int slot[4];
        #pragma unroll
        for (int k = 0; k < 4; ++k) {
            slot[k] = 0;
            if (q == 0 && val[k]) slot[k] = atomicAdd(&cnt[d[k]], 1);
        }

        // ---- [4] process the 4 edges ----
        #pragma unroll
        for (int k = 0; k < 4; ++k) {
            if (!val[k]) continue;   // all 4 lanes of a group share val[k]
            int sl = __shfl(slot[k], lbase);

            float pd = heq[k].x * av.x + heq[k].y * av.y + heq[k].z * av.z + heq[k].w * av.w;
            pd += __shfl_xor(pd, 1);
            pd += __shfl_xor(pd, 2);
            float score = svs[k].x + svd[k].y + pd;

            float4 o1 = shfl_xor4(hq[k], 1);
            float4 o2 = shfl_xor4(hq[k], 2);
            float4 o3 = shfl_xor4(o1, 2);
            bool q0 = (q == 0), q1 = (q == 1), q2 = (q == 2);
            float4 row0 = q0 ? hq[k] : q1 ? o1 : q2 ? o2 : o3;
            float4 row1 = q0 ? o1 : q1 ? hq[k] : q2 ? o3 : o2;
            float4 row2 = q0 ? o2 : q1 ? o3 : q2 ? hq[k] : o1;
            float4 row3 = q0 ? o3 : q1 ? o2 : q2 ? o1 : hq[k];
            float hs[16] = {row0.x,row0.y,row0.z,row0.w, row1.x,row1.y,row1.z,row1.w,
                            row2.x,row2.y,row2.z,row2.w, row3.x,row3.y,row3.z,row3.w};

            const float* wb = lw + (size_t)r[k] * LDS_STRIDE + q * 4;
            float4 acc = {0.f, 0.f, 0.f, 0.f};
            #pragma unroll
            for (int i = 0; i < 16; ++i) {
                float4 w = *(const float4*)(wb + i * 16);
                float hv = hs[i];
                acc.x += hv * w.x; acc.y += hv * w.y; acc.z += hv * w.z; acc.w += hv * w.w;
            }
            acc.x *= score; acc.y *= score; acc.z *= score; acc.w *= score;

            if (sl < CAP) {
                *(float4*)(bucket + ((size_t)d[k] * CAP + sl) * OUT_DIM + q * 4) = acc;
            } else {
                float* outp = hout + (size_t)d[k] * OUT_DIM + q * 4;
                atomicAdd(outp + 0, acc.x);
                atomicAdd(outp + 1, acc.y);
                atomicAdd(outp + 2, acc.z);
                atomicAdd(outp + 3, acc.w);
            }
        }
    }
}

// ---------------------------------------------------------------------------
// Reduce: 16 lanes/node (quarter q x stream p), 4 parallel j-streams, 2-step
// butterfly. Plain store for deg<=CAP, atomicAdd for deg>CAP (overflow part
// already accumulated in hout).
// ---------------------------------------------------------------------------
__global__ __launch_bounds__(256) void reduce_bucket_kernel(
    const float* __restrict__ bucket,
    const int* __restrict__ cnt,
    float* __restrict__ hout)
{
    int tid = blockIdx.x * 256 + threadIdx.x;
    int n = tid >> 4;
    int l = tid & 15;
    int q = l & 3;
    int p = l >> 2;      // 0..3: j-stream
    if (n >= N_NODES) return;

    int deg = cnt[n];
    int m = deg > CAP ? CAP : deg;
    const float4* bp = (const float4*)(bucket + (size_t)n * CAP * OUT_DIM) + q;
    float4 acc = {0.f, 0.f, 0.f, 0.f};
    for (int j = p; j < m; j += 4) {
        float4 v = bp[j * 4];
        acc.x += v.x; acc.y += v.y; acc.z += v.z; acc.w += v.w;
    }
    acc.x += __shfl_xor(acc.x, 4); acc.y += __shfl_xor(acc.y, 4);
    acc.z += __shfl_xor(acc.z, 4); acc.w += __shfl_xor(acc.w, 4);
    acc.x += __shfl_xor(acc.x, 8); acc.y += __shfl_xor(acc.y, 8);
    acc.z += __shfl_xor(acc.z, 8); acc.w += __shfl_xor(acc.w, 8);

    if (p == 0) {
        if (deg <= CAP) {
            *(float4*)(hout + (size_t)n * OUT_DIM + q * 4) = acc;
        } else {
            float* outp = hout + (size_t)n * OUT_DIM + q * 4;
            atomicAdd(outp + 0, acc.x);
            atomicAdd(outp + 1, acc.y);
            atomicAdd(outp + 2, acc.z);
            atomicAdd(outp + 3, acc.w);
        }
    }
}

// ===========================================================================
// Fallback (ws too small): direct atomic scatter (known-correct).
// ===========================================================================
__global__ __launch_bounds__(256) void prep_kernel(
    const float* __restrict__ Ws, const float* __restrict__ Wa,
    const float* __restrict__ weight, const float* __restrict__ w_comp,
    float* __restrict__ Wrel, float* __restrict__ avec)
{
    int f = blockIdx.x * blockDim.x + threadIdx.x;
    if (f < N_RELS * IN_DIM * OUT_DIM) {
        int a   = f / (N_RELS * OUT_DIM);
        int rem = f % (N_RELS * OUT_DIM);
        int r   = rem / OUT_DIM;
        int o   = rem % OUT_DIM;
        float acc = 0.f;
        #pragma unroll
        for (int b = 0; b < N_BASES; ++b)
            acc += w_comp[r * N_BASES + b] * weight[a * (N_BASES * OUT_DIM) + b * OUT_DIM + o];
        Wrel[f] = acc;
    } else if (f < N_RELS * IN_DIM * OUT_DIM + 48) {
        int g = f - N_RELS * IN_DIM * OUT_DIM;
        int k = g / IN_DIM;
        int i = g % IN_DIM;
        float acc = 0.f;
        #pragma unroll
        for (int o = 0; o < OUT_DIM; ++o)
            acc += Wa[k * OUT_DIM + o] * Ws[o * IN_DIM + i];
        avec[g] = acc;
    }
}

__global__ __launch_bounds__(256) void edge_atomic_kernel(
    const float* __restrict__ h,
    const float* __restrict__ he,
    const int* __restrict__ src,
    const int* __restrict__ dst,
    const int* __restrict__ rel,
    const float* __restrict__ Wrel,
    const float* __restrict__ avec,
    float* __restrict__ hout)
{
    int e = blockIdx.x * blockDim.x + threadIdx.x;
    if (e >= N_EDGES) return;
    int s = src[e], d = dst[e], r = rel[e];
    float hs[IN_DIM];
    const float4* p = (const float4*)(h + (size_t)s * IN_DIM);
    #pragma unroll
    for (int i = 0; i < 4; ++i) {
        float4 v = p[i];
        hs[4*i+0] = v.x; hs[4*i+1] = v.y; hs[4*i+2] = v.z; hs[4*i+3] = v.w;
    }
    float score = 0.f;
    #pragma unroll
    for (int i = 0; i < IN_DIM; ++i) score += hs[i] * avec[i];
    const float4* qe = (const float4*)(he + (size_t)e * IN_DIM);
    #pragma unroll
    for (int i = 0; i < 4; ++i) {
        float4 v = qe[i];
        score += v.x * avec[16+4*i] + v.y * avec[17+4*i] + v.z * avec[18+4*i] + v.w * avec[19+4*i];
    }
    const float4* pd = (const float4*)(h + (size_t)d * IN_DIM);
    #pragma unroll
    for (int i = 0; i < 4; ++i) {
        float4 v = pd[i];
        score += v.x * avec[32+4*i] + v.y * avec[33+4*i] + v.z * avec[34+4*i] + v.w * avec[35+4*i];
    }
    float acc[OUT_DIM];
    #pragma unroll
    for (int o = 0; o < OUT_DIM; ++o) acc[o] = 0.f;
    const float* W = Wrel + (size_t)r * 256;
    #pragma unroll
    for (int i = 0; i < IN_DIM; ++i) {
        float hv = hs[i];
        #pragma unroll
        for (int o = 0; o < OUT_DIM; ++o) acc[o] += hv * W[i * OUT_DIM + o];
    }
    float* outp = hout + (size_t)d * OUT_DIM;
    #pragma unroll
    for (int o = 0; o < OUT_DIM; ++o) atomicAdd(outp + o, acc[o] * score);
}

extern "C" void kernel_launch(void* const* d_in, const int* in_sizes, int n_in,
                              void* d_out, int out_size, void* d_ws, size_t ws_size,
                              hipStream_t stream) {
    const float* h      = (const float*)d_in[0];
    const float* he     = (const float*)d_in[1];
    const float* Ws     = (const float*)d_in[2];
    const float* Wa     = (const float*)d_in[3];
    const float* weight = (const float*)d_in[4];
    const float* w_comp = (const float*)d_in[5];
    const int*   src    = (const int*)d_in[6];
    const int*   dst    = (const int*)d_in[7];
    const int*   rel    = (const int*)d_in[8];
    float* hout = (float*)d_out;

    // ws layout (float offsets)
    const size_t OFF_WREL   = 0;         // 23040 f
    const size_t OFF_AVEC   = 23040;     // 48 f (+16 pad)
    const size_t OFF_S13    = 23104;     // 100000 f
    const size_t OFF_CNT    = 123104;    // 50000 i
    const size_t OFF_BUCKET = 173104;    // N*CAP*16 f (16-f aligned)
    const size_t NEED_BUCKET = (OFF_BUCKET + (size_t)N_NODES * CAP * OUT_DIM) * 4;

    float* wsf  = (float*)d_ws;
    float* Wrel = wsf + OFF_WREL;
    float* avec = wsf + OFF_AVEC;
    float2* s13 = (float2*)(wsf + OFF_S13);
    int* cnt    = (int*)(wsf + OFF_CNT);

    if (ws_size >= NEED_BUCKET) {
        float* bucket = wsf + OFF_BUCKET;

        setup_kernel<<<PREP_BLOCKS + DOTS_BLOCKS + ZERO_BLOCKS + HZ_BLOCKS, 256, 0, stream>>>(
            Ws, Wa, weight, w_comp, h, Wrel, avec, s13, cnt, hout);
        compute_lds_kernel<<<N_EDGES / EDGES_PER_BLK, 1024,
                             N_RELS * LDS_STRIDE * sizeof(float), stream>>>(
            h, he, src, dst, rel, Wrel, avec, s13, cnt, bucket, hout);
        reduce_bucket_kernel<<<(N_NODES * 16 + 255) / 256, 256, 0, stream>>>(
            bucket, cnt, hout);
    } else {
        hipMemsetAsync(d_out, 0, (size_t)out_size * sizeof(float), stream);
        int total = N_RELS * IN_DIM * OUT_DIM + 48;
        prep_kernel<<<(total + 255) / 256, 256, 0, stream>>>(Ws, Wa, weight, w_comp, Wrel, avec);
        edge_atomic_kernel<<<(N_EDGES + 255) / 256, 256, 0, stream>>>(
            h, he, src, dst, rel, Wrel, avec, hout);
    }
}